// Round 8
// baseline (295.877 us; speedup 1.0000x reference)
//
#include <hip/hip_runtime.h>
#include <hip/hip_bf16.h>

#define T_TRIP 500000
#define NP     100000
#define NTILES 7813    // ceil(T_TRIP/64)
#define NPAD   500032  // NTILES*64
#define CHUNK  11      // tiles per block, 768 blocks * 11 = 8448 >= NTILES

typedef float f32x4 __attribute__((ext_vector_type(4)));
typedef __bf16 bf16x8 __attribute__((ext_vector_type(8)));
typedef unsigned short u16;
typedef unsigned short u16x8 __attribute__((ext_vector_type(8)));
typedef unsigned int u32;

__device__ __forceinline__ u16 f2bf(float f) {
  union { float f; unsigned u; } v; v.f = f;
  unsigned r = v.u + 0x7fffu + ((v.u >> 16) & 1u);
  return (u16)(r >> 16);
}

__device__ __forceinline__ ushort4 cvt4(float4 v) {
  ushort4 o; o.x = f2bf(v.x); o.y = f2bf(v.y); o.z = f2bf(v.z); o.w = f2bf(v.w);
  return o;
}

__device__ __forceinline__ u16 cvt1_pk(float v) {
  unsigned r;
  asm("v_cvt_pk_bf16_f32 %0, %1, %1" : "=v"(r) : "v"(v));
  return (u16)r;
}

__device__ __forceinline__ float bflo(u32 d) {
  union { u32 u; float f; } v; v.u = d << 16; return v.f;
}
__device__ __forceinline__ float bfhi(u32 d) {
  union { u32 u; float f; } v; v.u = d & 0xffff0000u; return v.f;
}

#define MFMA16(a, b, c) __builtin_amdgcn_mfma_f32_16x16x32_bf16((a), (b), (c), 0, 0, 0)

#define WAITVM(N) asm volatile("s_waitcnt vmcnt(" #N ")" ::: "memory")
#define LGKM0()   asm volatile("s_waitcnt lgkmcnt(0)" ::: "memory")

__device__ __forceinline__ void barrier_raw() {
  asm volatile("" ::: "memory");
  __builtin_amdgcn_s_barrier();
  asm volatile("" ::: "memory");
  __builtin_amdgcn_sched_barrier(0);
}

__device__ __forceinline__ void gload_lds16(const u16* g, u16* l) {
  __builtin_amdgcn_global_load_lds((const __attribute__((address_space(1))) void*)g,
                                   (__attribute__((address_space(3))) void*)l, 16, 0, 0);
}
__device__ __forceinline__ void gload_lds4(const int* g, int* l) {
  __builtin_amdgcn_global_load_lds((const __attribute__((address_space(1))) void*)g,
                                   (__attribute__((address_space(3))) void*)l, 4, 0, 0);
}

// =================== ws layout ===================
#define FP_W1A   0u
#define FP_W1B   16384u
#define FP_W1C   32768u
#define FP_W2    49152u
#define FP_PW1   65536u
#define FP_PW2   98304u
#define FP_W1D   114688u    // f32 [4][128]
#define FP_H     131072u    // h_pair bf16 [NP][128]
#define FP_AGG   12931072u  // agg bf16 [NP][128]
// sorted-path byte offsets:
#define SB_CNT2    51462144ull
#define SB_CURSOR2 51862144ull
#define SB_BSUM2   52262144ull
#define SB_TRIP    52262656ull          // 16B packed AoS per triplet, NPAD entries
#define WS_S2      60263168ull

#define HSTR   136   // pair-kernel hidden stride (u16)
#define HSTR2  132   // triplet hidden/m stride (u16); 66 dw
#define GSTR   520   // XB group stride (u16)
#define X2STR  264   // pair-input tile stride (u16)

// ---------------- fused pre: weights + hconv/aggzero + hist ----------------
__global__ void k_pre(const float* __restrict__ psi_w1, const float* __restrict__ psi_w2,
                      const float* __restrict__ phi_w1, const float* __restrict__ phi_w2,
                      const float* __restrict__ h, const int* __restrict__ ivw,
                      u16* __restrict__ ws, int* __restrict__ cnt) {
  const int b = blockIdx.x;
  if (b < 450) {                       // ---- weight prep ----
    int i = b * 256 + threadIdx.x;
    if (i < 49152) {
      int s = i / 16384, r = i % 16384;
      int n = r / 128, k = r % 128;
      ws[FP_W1A + i] = f2bf(psi_w1[(s * 128 + k) * 128 + n]);
      return;
    }
    i -= 49152;
    if (i < 16384) {
      int n = i / 128, k = i % 128;
      ws[FP_W2 + i] = f2bf(psi_w2[k * 128 + n]);
      return;
    }
    i -= 16384;
    if (i < 32768) {
      int n = i / 256, k = i % 256;
      ws[FP_PW1 + i] = f2bf(phi_w1[k * 128 + n]);
      return;
    }
    i -= 32768;
    if (i < 16384) {
      int n = i / 128, k = i % 128;
      ws[FP_PW2 + i] = f2bf(phi_w2[k * 128 + n]);
      return;
    }
    i -= 16384;
    if (i < 512) {
      int k = i / 128, n = i % 128;
      reinterpret_cast<float*>(ws + FP_W1D)[i] = psi_w1[(384 + k) * 128 + n];
    }
  } else if (b < 6700) {               // ---- h->bf16 + zero AGG ----
    const size_t i = (size_t)((b - 450) * 256 + threadIdx.x) * 8;
    float4 v0 = *reinterpret_cast<const float4*>(h + i);
    float4 v1 = *reinterpret_cast<const float4*>(h + i + 4);
    *reinterpret_cast<ushort4*>(ws + FP_H + i)     = cvt4(v0);
    *reinterpret_cast<ushort4*>(ws + FP_H + i + 4) = cvt4(v1);
    ushort4 z = {0, 0, 0, 0};
    *reinterpret_cast<ushort4*>(ws + FP_AGG + i)     = z;
    *reinterpret_cast<ushort4*>(ws + FP_AGG + i + 4) = z;
  } else {                             // ---- histogram ----
    int i = (b - 6700) * 256 + threadIdx.x;
    if (i < T_TRIP) atomicAdd(&cnt[ivw[i]], 1);
  }
}

// ================= scan =================
__global__ __launch_bounds__(1024) void k_scan1(const int* __restrict__ cnt,
                                                int* __restrict__ cursor, int* __restrict__ bsum) {
  __shared__ int wsum[16];
  const int idx = blockIdx.x * 1024 + threadIdx.x;
  const int lane = threadIdx.x & 63, wid = threadIdx.x >> 6;
  int v = (idx < NP) ? cnt[idx] : 0;
  int x = v;
#pragma unroll
  for (int off = 1; off < 64; off <<= 1) {
    int n = __shfl_up(x, off);
    if (lane >= off) x += n;
  }
  if (lane == 63) wsum[wid] = x;
  __syncthreads();
  if (threadIdx.x < 16) {
    int s = wsum[threadIdx.x];
#pragma unroll
    for (int off = 1; off < 16; off <<= 1) {
      int n = __shfl_up(s, off);
      if (threadIdx.x >= off) s += n;
    }
    wsum[threadIdx.x] = s;
  }
  __syncthreads();
  const int base = wid ? wsum[wid - 1] : 0;
  if (idx < NP) cursor[idx] = base + x - v;      // block-local exclusive
  if (threadIdx.x == 1023) bsum[blockIdx.x] = base + x;
}

__global__ void k_scan2(int* __restrict__ bsum) {
  __shared__ int s[128];
  const int t = threadIdx.x;
  int v = (t < 98) ? bsum[t] : 0;
  s[t] = v; __syncthreads();
#pragma unroll
  for (int off = 1; off < 128; off <<= 1) {
    int a = (t >= off) ? s[t - off] : 0;
    __syncthreads();
    s[t] += a;
    __syncthreads();
  }
  if (t < 98) bsum[t] = s[t] - v;                // exclusive block bases
}

// ================= permute -> 16B packed AoS (bsum folded in) =================
// d0 = ivu | (ivw&0x7fff)<<17 ; d1 = iuw | (ivw>>15)<<17 ; d2,d3 = geom bf16x4
__global__ void k_perm_pack(const int* __restrict__ ivu, const int* __restrict__ iuw,
                            const int* __restrict__ ivw, const float* __restrict__ geom,
                            int* __restrict__ cursor, const int* __restrict__ bsum,
                            int4* __restrict__ trip) {
  int i = blockIdx.x * 256 + threadIdx.x;
  if (i < T_TRIP) {
    int v = ivw[i];
    int pos = atomicAdd(&cursor[v], 1) + bsum[v >> 10];
    float4 g = reinterpret_cast<const float4*>(geom)[i];
    u32 pk0, pk1;
    asm("v_cvt_pk_bf16_f32 %0, %1, %2" : "=v"(pk0) : "v"(g.x), "v"(g.y));
    asm("v_cvt_pk_bf16_f32 %0, %1, %2" : "=v"(pk1) : "v"(g.z), "v"(g.w));
    int4 rec;
    rec.x = ivu[i] | ((v & 0x7fff) << 17);
    rec.y = iuw[i] | ((v >> 15) << 17);
    rec.z = (int)pk0;
    rec.w = (int)pk1;
    trip[pos] = rec;
  } else if (i < NPAD) {
    int4 z = {0, 0, 0, 0};
    trip[i] = z;
  }
}

// ================= sorted triplet kernel (R6 body, contiguous chunks + XCD swizzle) =================
__global__ __launch_bounds__(256, 3) void k_triplet_sortagg(
    const u16* __restrict__ H, const int* __restrict__ trip,
    const u16* __restrict__ W1A, const u16* __restrict__ W1B, const u16* __restrict__ W1C,
    const float* __restrict__ w1dF, const u16* __restrict__ W2T,
    const float* __restrict__ b1, const float* __restrict__ b2,
    u16* __restrict__ AGG) {
  __shared__ __align__(16) u16 XB[2][16 * GSTR];   // 33280 B
  __shared__ __align__(16) u16 hl[64 * HSTR2];     // 16896 B (also m-tile)
  __shared__ __align__(16) int aosT[2][256];       //  2048 B   total 52224 B -> 3 blocks/CU

  u32* mlu = reinterpret_cast<u32*>(hl);

  const int tid = threadIdx.x;
  const int w = tid >> 6, l = tid & 63;
  const int lr = l & 15;
  const int lk = (l >> 4) << 3;
  const int n0 = w * 32 + lr;
  const int rowh = (l >> 4) << 2;
  const int srow = l >> 4;
  const int schunk = (l & 15) ^ ((l >> 4) << 1);

  // contiguous chunk per block, bijective XCD swizzle (768 = 8 XCD * 96 chunks)
  const int c = ((blockIdx.x & 7) * 96) + (blockIdx.x >> 3);
  const int tb = c * CHUNK;
  if (tb >= NTILES) return;
  int te = tb + CHUNK; if (te > NTILES) te = NTILES;

  // hoisted constants (W2 frags in regs -> GEMM2 has no vmem)
  bf16x8 w2f[4][2];
#pragma unroll
  for (int ks = 0; ks < 4; ++ks)
#pragma unroll
    for (int ct = 0; ct < 2; ++ct)
      w2f[ks][ct] = *reinterpret_cast<const bf16x8*>(&W2T[(size_t)(n0 + ct * 16) * 128 + ks * 32 + lk]);
  const float b1v[2] = {b1[n0], b1[n0 + 16]};
  const float b2v[2] = {b2[n0], b2[n0 + 16]};
  float w1dv[4][2];
#pragma unroll
  for (int k = 0; k < 4; ++k) {
    w1dv[k][0] = w1dF[k * 128 + n0];
    w1dv[k][1] = w1dF[k * 128 + n0 + 16];
  }

  auto get_idx = [&](int cb, int r, int sel) -> int {
    if (sel == 0) return aosT[cb][r * 4] & 0x1FFFF;
    if (sel == 1) return aosT[cb][r * 4 + 1] & 0x1FFFF;
    u32 d0 = (u32)aosT[cb][r * 4], d1 = (u32)aosT[cb][r * 4 + 1];
    return (int)((d0 >> 17) | ((d1 >> 17) << 15));
  };

  auto stage_src = [&](int cb, int sel, int buf) {
#pragma unroll
    for (int q = 0; q < 4; ++q) {
      const int g = w * 4 + q;
      const int idx = get_idx(cb, g * 4 + srow, sel);      // LDS broadcast
      gload_lds16(H + (size_t)idx * 128 + schunk * 8, &XB[buf][g * GSTR]);
    }
  };

  auto stage_aos = [&](int tile, int cb) {                  // 1 vm-op per wave
    const int* src = trip + (size_t)tile * 256;
    gload_lds4(src + w * 64 + l, &aosT[cb][w * 64]);
  };

  auto gemm_src = [&](const u16* WT, int buf, f32x4 (&acc)[4][2]) {
#pragma unroll
    for (int ks = 0; ks < 4; ++ks) {
      bf16x8 a[4], b[2];
#pragma unroll
      for (int rt = 0; rt < 4; ++rt) {
        const int r = rt * 16 + lr;
        const int g = r >> 2, s = r & 3;
        const int j = ks * 4 + (l >> 4);
        a[rt] = *reinterpret_cast<const bf16x8*>(&XB[buf][g * GSTR + s * 128 + ((j ^ (s << 1)) << 3)]);
      }
#pragma unroll
      for (int ct = 0; ct < 2; ++ct)
        b[ct] = *reinterpret_cast<const bf16x8*>(&WT[(size_t)(n0 + ct * 16) * 128 + ks * 32 + lk]);
#pragma unroll
      for (int rt = 0; rt < 4; ++rt)
#pragma unroll
        for (int ct = 0; ct < 2; ++ct)
          acc[rt][ct] = MFMA16(a[rt], b[ct], acc[rt][ct]);
    }
  };

  int cur = 0, pb = 0;

  // ---- prologue: AoS tiles tb and tb+1, then s0(tb) ----
  {
    int t1 = tb + 1; if (t1 >= NTILES) t1 = NTILES - 1;
    stage_aos(tb, 0);
    stage_aos(t1, 1);
    WAITVM(0);
    barrier_raw();
    stage_src(0, 0 /*ivu*/, 0);
  }

  for (int tt = tb; tt < te; ++tt) {
    const int t0 = tt * 64;

    stage_src(cur, 1 /*iuw*/, pb ^ 1);       // A: s1(t)
    WAITVM(4);                               // s0 resident
    barrier_raw();

    f32x4 acc[4][2] = {};
    gemm_src(W1A, pb, acc);                  // D
    barrier_raw();                           // XB[pb] free

    stage_src(cur, 2 /*ivw*/, pb);           // F: s2(t)
    WAITVM(4);                               // s1 resident
    barrier_raw();

    gemm_src(W1B, pb ^ 1, acc);              // I
    WAITVM(0);                               // s2 resident
    barrier_raw();                           // XB[pb^1] free

    stage_src(cur ^ 1, 0 /*ivu*/, pb ^ 1);   // L: s0(t+1)
    gemm_src(W1C, pb, acc);                  // M

    // N: geom (bf16 from AoS) + bias + silu -> hl
#pragma unroll
    for (int rt = 0; rt < 4; ++rt)
#pragma unroll
      for (int j = 0; j < 4; ++j) {
        const int row = rt * 16 + rowh + j;
        const u32 d2 = (u32)aosT[cur][row * 4 + 2];
        const u32 d3 = (u32)aosT[cur][row * 4 + 3];
        const float gx = bflo(d2), gy = bfhi(d2), gz = bflo(d3), gw = bfhi(d3);
#pragma unroll
        for (int ct = 0; ct < 2; ++ct)
          acc[rt][ct][j] += gx * w1dv[0][ct] + gy * w1dv[1][ct] +
                            gz * w1dv[2][ct] + gw * w1dv[3][ct];
      }
#pragma unroll
    for (int rt = 0; rt < 4; ++rt)
#pragma unroll
      for (int ct = 0; ct < 2; ++ct) {
        const float bb = b1v[ct];
#pragma unroll
        for (int j = 0; j < 4; ++j) {
          float v = acc[rt][ct][j] + bb;
          v = v * __builtin_amdgcn_rcpf(1.f + __expf(-v));
          hl[(rt * 16 + rowh + j) * HSTR2 + n0 + ct * 16] = cvt1_pk(v);
        }
      }
    LGKM0();
    barrier_raw();

    // P: GEMM2 (hl + reg W2 only)
    f32x4 acc2[4][2] = {};
#pragma unroll
    for (int ks = 0; ks < 4; ++ks) {
      bf16x8 a[4];
#pragma unroll
      for (int rt = 0; rt < 4; ++rt)
        a[rt] = *reinterpret_cast<const bf16x8*>(&hl[(rt * 16 + lr) * HSTR2 + ks * 32 + lk]);
#pragma unroll
      for (int rt = 0; rt < 4; ++rt)
#pragma unroll
        for (int ct = 0; ct < 2; ++ct)
          acc2[rt][ct] = MFMA16(a[rt], w2f[ks][ct], acc2[rt][ct]);
    }
    barrier_raw();                           // hl readers done -> reuse as m-tile

    // Q: pack bf16 pairs -> m-tile in LDS (stride 66 dwords)
#pragma unroll
    for (int rt = 0; rt < 4; ++rt)
#pragma unroll
      for (int j = 0; j < 4; ++j) {
        const int row = rt * 16 + rowh + j;
        float v0 = acc2[rt][0][j] + b2v[0];
        float v1 = acc2[rt][1][j] + b2v[1];
        float x0 = __shfl_xor(v0, 1);
        float x1 = __shfl_xor(v1, 1);
        const bool even = (l & 1) == 0;
        float lo = even ? v0 : x1;
        float hi = even ? x0 : v1;
        const int dcol = even ? (n0 >> 1) : ((n0 + 15) >> 1);
        u32 pk;
        asm("v_cvt_pk_bf16_f32 %0, %1, %2" : "=v"(pk) : "v"(lo), "v"(hi));
        mlu[row * 66 + dcol] = pk;
      }
    LGKM0();
    barrier_raw();

    // R: segmented reduce over sorted vw; one pk-atomic per run per packed col
    {
      auto get_vw = [&](int r) -> int {
        u32 d0 = (u32)aosT[cur][r * 4], d1 = (u32)aosT[cur][r * 4 + 1];
        return (int)((d0 >> 17) | ((d1 >> 17) << 15));
      };
      float lo = 0.f, hi = 0.f;
      int vwc = get_vw(w * 16);
#pragma unroll 1
      for (int r8 = 0; r8 < 16; ++r8) {
        const int row = w * 16 + r8;
        const u32 d = mlu[row * 66 + l];
        if (t0 + row < T_TRIP) { lo += bflo(d); hi += bfhi(d); }
        const int vwn = (row < 63) ? get_vw(row + 1) : -1;
        if ((r8 == 15) || (vwn != vwc)) {
          u16* p = AGG + (size_t)vwc * 128 + l * 2;
          u32 pk;
          asm("v_cvt_pk_bf16_f32 %0, %1, %2" : "=v"(pk) : "v"(lo), "v"(hi));
          asm volatile("global_atomic_pk_add_bf16 %0, %1, off" :: "v"(p), "v"(pk) : "memory");
          lo = 0.f; hi = 0.f; vwc = vwn;
        }
      }
    }
    barrier_raw();                           // aosT[cur] free

    // O: AoS prefetch tile t+2 into aosT[cur]
    {
      int t2 = tt + 2; if (t2 >= NTILES) t2 = NTILES - 1;
      stage_aos(t2, cur);
    }

    WAITVM(0);                               // drain atomics + s0(t+1) + aos
    barrier_raw();
    pb ^= 1; cur ^= 1;
  }
  WAITVM(0);
}

// ================= pair kernel (R2-proven) =================
__global__ __launch_bounds__(256, 3) void k_pair_fast(
    const float* __restrict__ h_pair, const u16* __restrict__ H, const u16* __restrict__ AGG,
    const u16* __restrict__ PW1T, const u16* __restrict__ PW2T,
    const float* __restrict__ b1, const float* __restrict__ b2,
    float* __restrict__ out) {
  __shared__ __align__(16) u16 xl[64 * X2STR];
  __shared__ __align__(16) u16 hl[64 * HSTR];

  const int tid = threadIdx.x;
  const int r0 = blockIdx.x * 64;

  {
    const int row = tid >> 2, q = tid & 3;
    int rc = r0 + row; rc = (rc < NP) ? rc : (NP - 1);
    const u16x8* sh = reinterpret_cast<const u16x8*>(H + (size_t)rc * 128 + q * 32);
    const u16x8* sa = reinterpret_cast<const u16x8*>(AGG + (size_t)rc * 128 + q * 32);
    u16x8* d1 = reinterpret_cast<u16x8*>(&xl[row * X2STR + q * 32]);
    u16x8* d2 = reinterpret_cast<u16x8*>(&xl[row * X2STR + 128 + q * 32]);
#pragma unroll
    for (int i = 0; i < 4; ++i) { d1[i] = sh[i]; d2[i] = sa[i]; }
  }
  __syncthreads();

  const int w = tid >> 6, l = tid & 63;
  const int lr = l & 15;
  const int lk = (l >> 4) << 3;
  const int n0 = w * 32 + lr;
  const int rowh = (l >> 4) << 2;

  f32x4 acc[4][2] = {};
#pragma unroll 1
  for (int ks = 0; ks < 8; ++ks) {
    const int k0 = ks * 32;
    bf16x8 a[4], b[2];
#pragma unroll
    for (int rt = 0; rt < 4; ++rt)
      a[rt] = *reinterpret_cast<const bf16x8*>(&xl[(rt * 16 + lr) * X2STR + k0 + lk]);
#pragma unroll
    for (int ct = 0; ct < 2; ++ct)
      b[ct] = *reinterpret_cast<const bf16x8*>(&PW1T[(size_t)(n0 + ct * 16) * 256 + k0 + lk]);
#pragma unroll
    for (int rt = 0; rt < 4; ++rt)
#pragma unroll
      for (int ct = 0; ct < 2; ++ct)
        acc[rt][ct] = MFMA16(a[rt], b[ct], acc[rt][ct]);
  }

  {
    const float b1v0 = b1[n0], b1v1 = b1[n0 + 16];
#pragma unroll
    for (int rt = 0; rt < 4; ++rt)
#pragma unroll
      for (int ct = 0; ct < 2; ++ct) {
        const float bb = ct ? b1v1 : b1v0;
#pragma unroll
        for (int j = 0; j < 4; ++j) {
          float v = acc[rt][ct][j] + bb;
          v = v * __builtin_amdgcn_rcpf(1.f + __expf(-v));
          hl[(rt * 16 + rowh + j) * HSTR + n0 + ct * 16] = cvt1_pk(v);
        }
      }
  }
  __syncthreads();

  f32x4 acc2[4][2] = {};
#pragma unroll
  for (int ks = 0; ks < 4; ++ks) {
    const int k0 = ks * 32;
    bf16x8 a[4], b[2];
#pragma unroll
    for (int rt = 0; rt < 4; ++rt)
      a[rt] = *reinterpret_cast<const bf16x8*>(&hl[(rt * 16 + lr) * HSTR + k0 + lk]);
#pragma unroll
    for (int ct = 0; ct < 2; ++ct)
      b[ct] = *reinterpret_cast<const bf16x8*>(&PW2T[(size_t)(n0 + ct * 16) * 128 + k0 + lk]);
#pragma unroll
    for (int rt = 0; rt < 4; ++rt)
#pragma unroll
      for (int ct = 0; ct < 2; ++ct)
        acc2[rt][ct] = MFMA16(a[rt], b[ct], acc2[rt][ct]);
  }

  {
    const float b2v0 = b2[n0], b2v1 = b2[n0 + 16];
#pragma unroll
    for (int rt = 0; rt < 4; ++rt)
#pragma unroll
      for (int j = 0; j < 4; ++j) {
        const int row = rt * 16 + rowh + j;
        const int r = r0 + row;
        if (r < NP) {
          out[(size_t)r * 128 + n0]      = h_pair[(size_t)r * 128 + n0]      + acc2[rt][0][j] + b2v0;
          out[(size_t)r * 128 + n0 + 16] = h_pair[(size_t)r * 128 + n0 + 16] + acc2[rt][1][j] + b2v1;
        }
      }
  }
}

// ===================== R0 fallback (tiny ws) =====================
#define PSI_W1T_OFF 0
#define PSI_W2T_OFF 53248
#define PHI_W1T_OFF 69632
#define PHI_W2T_OFF 102400
#define WS_U16_TOTAL 118784
#define XSTR 424

__global__ void k_prep(const float* __restrict__ psi_w1, const float* __restrict__ psi_w2,
                       const float* __restrict__ phi_w1, const float* __restrict__ phi_w2,
                       u16* __restrict__ ws) {
  int i = blockIdx.x * 256 + threadIdx.x;
  if (i < 128 * 416) {
    int n = i / 416, k = i % 416;
    ws[PSI_W1T_OFF + i] = f2bf(k < 388 ? psi_w1[k * 128 + n] : 0.f);
    return;
  }
  i -= 128 * 416;
  if (i < 128 * 128) {
    int n = i / 128, k = i % 128;
    ws[PSI_W2T_OFF + i] = f2bf(psi_w2[k * 128 + n]);
    return;
  }
  i -= 128 * 128;
  if (i < 128 * 256) {
    int n = i / 256, k = i % 256;
    ws[PHI_W1T_OFF + i] = f2bf(phi_w1[k * 128 + n]);
    return;
  }
  i -= 128 * 256;
  if (i < 128 * 128) {
    int n = i / 128, k = i % 128;
    ws[PHI_W2T_OFF + i] = f2bf(phi_w2[k * 128 + n]);
  }
}

__global__ __launch_bounds__(256, 2) void k_triplet(
    const float* __restrict__ h_pair,
    const int* __restrict__ ivu, const int* __restrict__ iuw, const int* __restrict__ ivw,
    const float* __restrict__ geom,
    const u16* __restrict__ W1T, const u16* __restrict__ W2T,
    const float* __restrict__ b1, const float* __restrict__ b2,
    float* __restrict__ agg) {
  __shared__ __align__(16) u16 xl[64 * XSTR];
  __shared__ __align__(16) u16 hl[64 * HSTR];
  __shared__ int svw[64];

  const int tid = threadIdx.x;
  const int t0 = blockIdx.x * 64;

  {
    const int row = tid >> 2, q = tid & 3;
    const int t = t0 + row;
    const int tc = (t < T_TRIP) ? t : (T_TRIP - 1);
    if (q == 0) svw[row] = (t < T_TRIP) ? ivw[tc] : -1;
    int idx[3];
    idx[0] = ivu[tc]; idx[1] = iuw[tc]; idx[2] = ivw[tc];
#pragma unroll
    for (int s = 0; s < 3; ++s) {
      const float4* src = reinterpret_cast<const float4*>(h_pair + (size_t)idx[s] * 128 + q * 32);
      u16* dst = &xl[row * XSTR + s * 128 + q * 32];
#pragma unroll
      for (int i = 0; i < 8; ++i)
        *reinterpret_cast<ushort4*>(dst + i * 4) = cvt4(src[i]);
    }
  }
  if (tid < 64) {
    const int t = t0 + tid;
    const int tc = (t < T_TRIP) ? t : (T_TRIP - 1);
    const float4 g = reinterpret_cast<const float4*>(geom)[tc];
    u16* dst = &xl[tid * XSTR + 384];
    *reinterpret_cast<ushort4*>(dst) = cvt4(g);
    ushort4 z = {0, 0, 0, 0};
#pragma unroll
    for (int i = 1; i < 8; ++i) *reinterpret_cast<ushort4*>(dst + i * 4) = z;
  }
  __syncthreads();

  const int w = tid >> 6;
  const int l = tid & 63;
  const int lr = l & 15;
  const int lk = (l >> 4) << 3;
  const int n0 = w * 32 + lr;
  const int rowh = (l >> 4) << 2;

  f32x4 acc[4][2] = {};
#pragma unroll 1
  for (int ks = 0; ks < 13; ++ks) {
    const int k0 = ks * 32;
    bf16x8 a[4], b[2];
#pragma unroll
    for (int rt = 0; rt < 4; ++rt)
      a[rt] = *reinterpret_cast<const bf16x8*>(&xl[(rt * 16 + lr) * XSTR + k0 + lk]);
#pragma unroll
    for (int ct = 0; ct < 2; ++ct)
      b[ct] = *reinterpret_cast<const bf16x8*>(&W1T[(size_t)(n0 + ct * 16) * 416 + k0 + lk]);
#pragma unroll
    for (int rt = 0; rt < 4; ++rt)
#pragma unroll
      for (int ct = 0; ct < 2; ++ct)
        acc[rt][ct] = MFMA16(a[rt], b[ct], acc[rt][ct]);
  }

  {
    const float b1v0 = b1[n0], b1v1 = b1[n0 + 16];
#pragma unroll
    for (int rt = 0; rt < 4; ++rt)
#pragma unroll
      for (int ct = 0; ct < 2; ++ct) {
        const float bb = ct ? b1v1 : b1v0;
#pragma unroll
        for (int j = 0; j < 4; ++j) {
          float v = acc[rt][ct][j] + bb;
          v = v / (1.f + __expf(-v));
          hl[(rt * 16 + rowh + j) * HSTR + n0 + ct * 16] = f2bf(v);
        }
      }
  }
  __syncthreads();

  f32x4 acc2[4][2] = {};
#pragma unroll
  for (int ks = 0; ks < 4; ++ks) {
    const int k0 = ks * 32;
    bf16x8 a[4], b[2];
#pragma unroll
    for (int rt = 0; rt < 4; ++rt)
      a[rt] = *reinterpret_cast<const bf16x8*>(&hl[(rt * 16 + lr) * HSTR + k0 + lk]);
#pragma unroll
    for (int ct = 0; ct < 2; ++ct)
      b[ct] = *reinterpret_cast<const bf16x8*>(&W2T[(size_t)(n0 + ct * 16) * 128 + k0 + lk]);
#pragma unroll
    for (int rt = 0; rt < 4; ++rt)
#pragma unroll
      for (int ct = 0; ct < 2; ++ct)
        acc2[rt][ct] = MFMA16(a[rt], b[ct], acc2[rt][ct]);
  }

  {
    const float b2v0 = b2[n0], b2v1 = b2[n0 + 16];
#pragma unroll
    for (int rt = 0; rt < 4; ++rt)
#pragma unroll
      for (int j = 0; j < 4; ++j) {
        const int row = rt * 16 + rowh + j;
        const int dst = svw[row];
        if (dst >= 0) {
          unsafeAtomicAdd(&agg[(size_t)dst * 128 + n0], acc2[rt][0][j] + b2v0);
          unsafeAtomicAdd(&agg[(size_t)dst * 128 + n0 + 16], acc2[rt][1][j] + b2v1);
        }
      }
  }
}

__global__ __launch_bounds__(256, 2) void k_pair(
    const float* __restrict__ h_pair,
    const u16* __restrict__ W1T, const u16* __restrict__ W2T,
    const float* __restrict__ b1, const float* __restrict__ b2,
    float* __restrict__ out) {
  __shared__ __align__(16) u16 xl[64 * X2STR];
  __shared__ __align__(16) u16 hl[64 * HSTR];

  const int tid = threadIdx.x;
  const int r0 = blockIdx.x * 64;

  {
    const int row = tid >> 2, q = tid & 3;
    const int r = r0 + row;
    const int rc = (r < NP) ? r : (NP - 1);
    const float4* s1 = reinterpret_cast<const float4*>(h_pair + (size_t)rc * 128 + q * 32);
    const float4* s2 = reinterpret_cast<const float4*>(out + (size_t)rc * 128 + q * 32);
    u16* d1 = &xl[row * X2STR + q * 32];
    u16* d2 = &xl[row * X2STR + 128 + q * 32];
#pragma unroll
    for (int i = 0; i < 8; ++i) {
      *reinterpret_cast<ushort4*>(d1 + i * 4) = cvt4(s1[i]);
      *reinterpret_cast<ushort4*>(d2 + i * 4) = cvt4(s2[i]);
    }
  }
  __syncthreads();

  const int w = tid >> 6;
  const int l = tid & 63;
  const int lr = l & 15;
  const int lk = (l >> 4) << 3;
  const int n0 = w * 32 + lr;
  const int rowh = (l >> 4) << 2;

  f32x4 acc[4][2] = {};
#pragma unroll 1
  for (int ks = 0; ks < 8; ++ks) {
    const int k0 = ks * 32;
    bf16x8 a[4], b[2];
#pragma unroll
    for (int rt = 0; rt < 4; ++rt)
      a[rt] = *reinterpret_cast<const bf16x8*>(&xl[(rt * 16 + lr) * X2STR + k0 + lk]);
#pragma unroll
    for (int ct = 0; ct < 2; ++ct)
      b[ct] = *reinterpret_cast<const bf16x8*>(&W1T[(size_t)(n0 + ct * 16) * 256 + k0 + lk]);
#pragma unroll
    for (int rt = 0; rt < 4; ++rt)
#pragma unroll
      for (int ct = 0; ct < 2; ++ct)
        acc[rt][ct] = MFMA16(a[rt], b[ct], acc[rt][ct]);
  }

  {
    const float b1v0 = b1[n0], b1v1 = b1[n0 + 16];
#pragma unroll
    for (int rt = 0; rt < 4; ++rt)
#pragma unroll
      for (int ct = 0; ct < 2; ++ct) {
        const float bb = ct ? b1v1 : b1v0;
#pragma unroll
        for (int j = 0; j < 4; ++j) {
          float v = acc[rt][ct][j] + bb;
          v = v / (1.f + __expf(-v));
          hl[(rt * 16 + rowh + j) * HSTR + n0 + ct * 16] = f2bf(v);
        }
      }
  }
  __syncthreads();

  f32x4 acc2[4][2] = {};
#pragma unroll
  for (int ks = 0; ks < 4; ++ks) {
    const int k0 = ks * 32;
    bf16x8 a[4], b[2];
#pragma unroll
    for (int rt = 0; rt < 4; ++rt)
      a[rt] = *reinterpret_cast<const bf16x8*>(&hl[(rt * 16 + lr) * HSTR + k0 + lk]);
#pragma unroll
    for (int ct = 0; ct < 2; ++ct)
      b[ct] = *reinterpret_cast<const bf16x8*>(&W2T[(size_t)(n0 + ct * 16) * 128 + k0 + lk]);
#pragma unroll
    for (int rt = 0; rt < 4; ++rt)
#pragma unroll
      for (int ct = 0; ct < 2; ++ct)
        acc2[rt][ct] = MFMA16(a[rt], b[ct], acc2[rt][ct]);
  }

  {
    const float b2v0 = b2[n0], b2v1 = b2[n0 + 16];
#pragma unroll
    for (int rt = 0; rt < 4; ++rt)
#pragma unroll
      for (int j = 0; j < 4; ++j) {
        const int row = rt * 16 + rowh + j;
        const int r = r0 + row;
        if (r < NP) {
          out[(size_t)r * 128 + n0]      = h_pair[(size_t)r * 128 + n0]      + acc2[rt][0][j] + b2v0;
          out[(size_t)r * 128 + n0 + 16] = h_pair[(size_t)r * 128 + n0 + 16] + acc2[rt][1][j] + b2v1;
        }
      }
  }
}

extern "C" void kernel_launch(void* const* d_in, const int* in_sizes, int n_in,
                              void* d_out, int out_size, void* d_ws, size_t ws_size,
                              hipStream_t stream) {
  const float* h_pair = (const float*)d_in[0];
  const int* ivu = (const int*)d_in[1];
  const int* iuw = (const int*)d_in[2];
  const int* ivw = (const int*)d_in[3];
  const float* geom = (const float*)d_in[4];
  const float* psi_w1 = (const float*)d_in[5];
  const float* psi_b1 = (const float*)d_in[6];
  const float* psi_w2 = (const float*)d_in[7];
  const float* psi_b2 = (const float*)d_in[8];
  const float* phi_w1 = (const float*)d_in[9];
  const float* phi_b1 = (const float*)d_in[10];
  const float* phi_w2 = (const float*)d_in[11];
  const float* phi_b2 = (const float*)d_in[12];

  float* out = (float*)d_out;
  u16* ws = (u16*)d_ws;
  char* wsb = (char*)d_ws;

  if (ws_size >= WS_S2) {
    int*  cnt    = (int*)(wsb + SB_CNT2);
    int*  cursor = (int*)(wsb + SB_CURSOR2);
    int*  bsum   = (int*)(wsb + SB_BSUM2);
    int4* trip   = (int4*)(wsb + SB_TRIP);

    hipMemsetAsync(cnt, 0, NP * sizeof(int), stream);
    k_pre<<<8654, 256, 0, stream>>>(psi_w1, psi_w2, phi_w1, phi_w2, h_pair, ivw, ws, cnt);
    k_scan1<<<98, 1024, 0, stream>>>(cnt, cursor, bsum);
    k_scan2<<<1, 128, 0, stream>>>(bsum);
    k_perm_pack<<<(NPAD + 255) / 256, 256, 0, stream>>>(ivu, iuw, ivw, geom, cursor, bsum, trip);
    k_triplet_sortagg<<<768, 256, 0, stream>>>(
        ws + FP_H, (const int*)trip,
        ws + FP_W1A, ws + FP_W1B, ws + FP_W1C,
        reinterpret_cast<const float*>(ws + FP_W1D), ws + FP_W2,
        psi_b1, psi_b2, ws + FP_AGG);
    k_pair_fast<<<(NP + 63) / 64, 256, 0, stream>>>(
        h_pair, ws + FP_H, ws + FP_AGG,
        ws + FP_PW1, ws + FP_PW2, phi_b1, phi_b2, out);
  } else {
    // ---------- R0 fallback ----------
    hipMemsetAsync(d_out, 0, (size_t)out_size * sizeof(float), stream);
    k_prep<<<(WS_U16_TOTAL + 255) / 256, 256, 0, stream>>>(psi_w1, psi_w2, phi_w1, phi_w2, ws);
    k_triplet<<<(T_TRIP + 63) / 64, 256, 0, stream>>>(
        h_pair, ivu, iuw, ivw, geom,
        ws + PSI_W1T_OFF, ws + PSI_W2T_OFF, psi_b1, psi_b2, out);
    k_pair<<<(NP + 63) / 64, 256, 0, stream>>>(
        h_pair, ws + PHI_W1T_OFF, ws + PHI_W2T_OFF, phi_b1, phi_b2, out);
  }
}

// Round 9
// 287.960 us; speedup vs baseline: 1.0275x; 1.0275x over previous
//
#include <hip/hip_runtime.h>
#include <hip/hip_bf16.h>

#define T_TRIP 500000
#define NP     100000
#define NTILES 7813    // ceil(T_TRIP/64)
#define NPAD   500032  // NTILES*64
#define NBATCH 31252   // NPAD/16

typedef float f32x4 __attribute__((ext_vector_type(4)));
typedef __bf16 bf16x8 __attribute__((ext_vector_type(8)));
typedef unsigned short u16;
typedef unsigned short u16x8 __attribute__((ext_vector_type(8)));
typedef unsigned int u32;

__device__ __forceinline__ u16 f2bf(float f) {
  union { float f; unsigned u; } v; v.f = f;
  unsigned r = v.u + 0x7fffu + ((v.u >> 16) & 1u);
  return (u16)(r >> 16);
}

__device__ __forceinline__ ushort4 cvt4(float4 v) {
  ushort4 o; o.x = f2bf(v.x); o.y = f2bf(v.y); o.z = f2bf(v.z); o.w = f2bf(v.w);
  return o;
}

__device__ __forceinline__ u16 cvt1_pk(float v) {
  unsigned r;
  asm("v_cvt_pk_bf16_f32 %0, %1, %1" : "=v"(r) : "v"(v));
  return (u16)r;
}

__device__ __forceinline__ float bflo(u32 d) {
  union { u32 u; float f; } v; v.u = d << 16; return v.f;
}
__device__ __forceinline__ float bfhi(u32 d) {
  union { u32 u; float f; } v; v.u = d & 0xffff0000u; return v.f;
}

#define MFMA16(a, b, c) __builtin_amdgcn_mfma_f32_16x16x32_bf16((a), (b), (c), 0, 0, 0)
#define LGKM0()   asm volatile("s_waitcnt lgkmcnt(0)" ::: "memory")

// =================== ws layout (u16 offsets for weight/H region) ===================
#define FP_W1A   0u
#define FP_W1B   16384u
#define FP_W1C   32768u
#define FP_W2    49152u
#define FP_PW1   65536u
#define FP_PW2   98304u
#define FP_W1D   114688u    // f32 [4][128]
#define FP_H     131072u    // h_pair bf16 [NP][128]
#define FP_AGG   12931072u  // Hagg bf16 [NP][128] (segment-summed silu activations)
// byte offsets:
#define SB_CNT2    51462144ull
#define SB_CURSOR2 51862144ull
#define SB_BSUM2   52262144ull
#define SB_TRIP    52262656ull          // 16B packed AoS per triplet, NPAD entries
#define SB_YA      60263168ull          // u32 [NP][64] (bf16-pair rows of H@W1a)
#define SB_YB      85863168ull
#define SB_YC     111463168ull
#define WS_S3     137063168ull

#define HSTR   136   // pair-kernel hidden stride (u16)
#define X2STR  264   // pair-input tile stride (u16)

// ---------------- pre: weights prep + zero Hagg + histogram ----------------
__global__ void k_pre3(const float* __restrict__ psi_w1, const float* __restrict__ psi_w2,
                       const float* __restrict__ phi_w1, const float* __restrict__ phi_w2,
                       const int* __restrict__ ivw,
                       u16* __restrict__ ws, int* __restrict__ cnt) {
  const int b = blockIdx.x;
  if (b < 450) {                       // ---- weight prep ----
    int i = b * 256 + threadIdx.x;
    if (i < 49152) {
      int s = i / 16384, r = i % 16384;
      int n = r / 128, k = r % 128;
      ws[FP_W1A + i] = f2bf(psi_w1[(s * 128 + k) * 128 + n]);
      return;
    }
    i -= 49152;
    if (i < 16384) {
      int n = i / 128, k = i % 128;
      ws[FP_W2 + i] = f2bf(psi_w2[k * 128 + n]);
      return;
    }
    i -= 16384;
    if (i < 32768) {
      int n = i / 256, k = i % 256;
      ws[FP_PW1 + i] = f2bf(phi_w1[k * 128 + n]);
      return;
    }
    i -= 32768;
    if (i < 16384) {
      int n = i / 128, k = i % 128;
      ws[FP_PW2 + i] = f2bf(phi_w2[k * 128 + n]);
      return;
    }
    i -= 16384;
    if (i < 512) {
      int k = i / 128, n = i % 128;
      reinterpret_cast<float*>(ws + FP_W1D)[i] = psi_w1[(384 + k) * 128 + n];
    }
  } else if (b < 3575) {               // ---- zero Hagg (12.8M u16) ----
    const size_t i = (size_t)((b - 450) * 256 + threadIdx.x) * 16;
    ushort4 z = {0, 0, 0, 0};
    u16* d = ws + FP_AGG + i;
#pragma unroll
    for (int k = 0; k < 4; ++k) *reinterpret_cast<ushort4*>(d + k * 4) = z;
  } else {                             // ---- histogram (1954 blocks) ----
    int i = (b - 3575) * 256 + threadIdx.x;
    if (i < T_TRIP) atomicAdd(&cnt[ivw[i]], 1);
  }
}

// ================= scan =================
__global__ __launch_bounds__(1024) void k_scan1(const int* __restrict__ cnt,
                                                int* __restrict__ cursor, int* __restrict__ bsum) {
  __shared__ int wsum[16];
  const int idx = blockIdx.x * 1024 + threadIdx.x;
  const int lane = threadIdx.x & 63, wid = threadIdx.x >> 6;
  int v = (idx < NP) ? cnt[idx] : 0;
  int x = v;
#pragma unroll
  for (int off = 1; off < 64; off <<= 1) {
    int n = __shfl_up(x, off);
    if (lane >= off) x += n;
  }
  if (lane == 63) wsum[wid] = x;
  __syncthreads();
  if (threadIdx.x < 16) {
    int s = wsum[threadIdx.x];
#pragma unroll
    for (int off = 1; off < 16; off <<= 1) {
      int n = __shfl_up(s, off);
      if (threadIdx.x >= off) s += n;
    }
    wsum[threadIdx.x] = s;
  }
  __syncthreads();
  const int base = wid ? wsum[wid - 1] : 0;
  if (idx < NP) cursor[idx] = base + x - v;      // block-local exclusive
  if (threadIdx.x == 1023) bsum[blockIdx.x] = base + x;
}

__global__ void k_scan2(int* __restrict__ bsum) {
  __shared__ int s[128];
  const int t = threadIdx.x;
  int v = (t < 98) ? bsum[t] : 0;
  s[t] = v; __syncthreads();
#pragma unroll
  for (int off = 1; off < 128; off <<= 1) {
    int a = (t >= off) ? s[t - off] : 0;
    __syncthreads();
    s[t] += a;
    __syncthreads();
  }
  if (t < 98) bsum[t] = s[t] - v;                // exclusive block bases
}

// ================= permute -> 16B packed AoS =================
// d0 = ivu | (ivw&0x7fff)<<17 ; d1 = iuw | (ivw>>15)<<17 ; d2,d3 = geom bf16x4
__global__ void k_perm_pack(const int* __restrict__ ivu, const int* __restrict__ iuw,
                            const int* __restrict__ ivw, const float* __restrict__ geom,
                            int* __restrict__ cursor, const int* __restrict__ bsum,
                            int4* __restrict__ trip) {
  int i = blockIdx.x * 256 + threadIdx.x;
  if (i < T_TRIP) {
    int v = ivw[i];
    int pos = atomicAdd(&cursor[v], 1) + bsum[v >> 10];
    float4 g = reinterpret_cast<const float4*>(geom)[i];
    u32 pk0, pk1;
    asm("v_cvt_pk_bf16_f32 %0, %1, %2" : "=v"(pk0) : "v"(g.x), "v"(g.y));
    asm("v_cvt_pk_bf16_f32 %0, %1, %2" : "=v"(pk1) : "v"(g.z), "v"(g.w));
    int4 rec;
    rec.x = ivu[i] | ((v & 0x7fff) << 17);
    rec.y = iuw[i] | ((v >> 15) << 17);
    rec.z = (int)pk0;
    rec.w = (int)pk1;
    trip[pos] = rec;
  } else if (i < NPAD) {
    int4 z = {0, 0, 0, 0};
    trip[i] = z;
  }
}

// ================= proj: h -> H bf16, Y_a/Y_b/Y_c = H @ W1{a,b,c}^T =================
__global__ __launch_bounds__(256, 4) void k_proj(
    const float* __restrict__ h, const u16* __restrict__ W1A, const u16* __restrict__ W1B,
    const u16* __restrict__ W1C, u16* __restrict__ H,
    u32* __restrict__ YA, u32* __restrict__ YB, u32* __restrict__ YC) {
  __shared__ __align__(16) u16 xs[64 * 132];   // 16896 B
  const int tid = threadIdx.x;
  const int r0 = blockIdx.x * 64;
  {
    const int row = tid >> 2, q = tid & 3;
    int rc = r0 + row; rc = (rc < NP) ? rc : (NP - 1);
    const float4* src = reinterpret_cast<const float4*>(h + (size_t)rc * 128 + q * 32);
    u16* ldst = &xs[row * 132 + q * 32];
    u16* gdst = H + (size_t)rc * 128 + q * 32;
#pragma unroll
    for (int i = 0; i < 8; ++i) {
      ushort4 c = cvt4(src[i]);
      *reinterpret_cast<ushort4*>(ldst + i * 4) = c;
      *reinterpret_cast<ushort4*>(gdst + i * 4) = c;
    }
  }
  __syncthreads();
  const int w = tid >> 6, l = tid & 63;
  const int lr = l & 15, lk = (l >> 4) << 3;
  const int n0 = w * 32 + lr;
  const int rowh = (l >> 4) << 2;

  const u16* WT[3] = {W1A, W1B, W1C};
  u32* YT[3] = {YA, YB, YC};
#pragma unroll
  for (int s = 0; s < 3; ++s) {
    f32x4 acc[4][2] = {};
#pragma unroll
    for (int ks = 0; ks < 4; ++ks) {
      bf16x8 a[4], b[2];
#pragma unroll
      for (int rt = 0; rt < 4; ++rt)
        a[rt] = *reinterpret_cast<const bf16x8*>(&xs[(rt * 16 + lr) * 132 + ks * 32 + lk]);
#pragma unroll
      for (int ct = 0; ct < 2; ++ct)
        b[ct] = *reinterpret_cast<const bf16x8*>(&WT[s][(size_t)(n0 + ct * 16) * 128 + ks * 32 + lk]);
#pragma unroll
      for (int rt = 0; rt < 4; ++rt)
#pragma unroll
        for (int ct = 0; ct < 2; ++ct)
          acc[rt][ct] = MFMA16(a[rt], b[ct], acc[rt][ct]);
    }
#pragma unroll
    for (int rt = 0; rt < 4; ++rt)
#pragma unroll
      for (int j = 0; j < 4; ++j) {
        const int row = rt * 16 + rowh + j;
        float v0 = acc[rt][0][j], v1 = acc[rt][1][j];
        float x0 = __shfl_xor(v0, 1), x1 = __shfl_xor(v1, 1);
        const bool even = (l & 1) == 0;
        float lo = even ? v0 : x1, hi = even ? x0 : v1;
        const int dcol = even ? (n0 >> 1) : ((n0 + 15) >> 1);
        if (r0 + row < NP) {
          u32 pk;
          asm("v_cvt_pk_bf16_f32 %0, %1, %2" : "=v"(pk) : "v"(lo), "v"(hi));
          YT[s][(size_t)(r0 + row) * 64 + dcol] = pk;
        }
      }
  }
}

// ================= gsilu: gather Y rows, sum+geom+b1, silu, run-reduce -> Hagg =================
// Barrier-free, LDS-free. Wave = 16 sorted triplets; lane l = cols 2l,2l+1.
__global__ void k_gsilu(
    const u32* __restrict__ YA, const u32* __restrict__ YB, const u32* __restrict__ YC,
    const u32* __restrict__ tripw, const float* __restrict__ w1dF,
    const float* __restrict__ b1, u16* __restrict__ Hagg) {
  const int w = threadIdx.x >> 6, l = threadIdx.x & 63;
  const int batch = blockIdx.x * 4 + w;
  if (batch >= NBATCH) return;
  const int t0 = batch * 16;

  // coalesced AoS read: 16 recs x 4 dwords
  const u32 aos = tripw[(size_t)batch * 64 + l];

  float wd[4][2];
#pragma unroll
  for (int k = 0; k < 4; ++k) {
    wd[k][0] = w1dF[k * 128 + 2 * l];
    wd[k][1] = w1dF[k * 128 + 2 * l + 1];
  }
  const float bb0 = b1[2 * l], bb1 = b1[2 * l + 1];

  int vw[16];
  u32 g2[16], g3[16], ga[16], gb[16], gc[16];
#pragma unroll
  for (int i = 0; i < 16; ++i) {
    const u32 d0 = (u32)__shfl((int)aos, i * 4);
    const u32 d1 = (u32)__shfl((int)aos, i * 4 + 1);
    g2[i] = (u32)__shfl((int)aos, i * 4 + 2);
    g3[i] = (u32)__shfl((int)aos, i * 4 + 3);
    vw[i] = (int)((d0 >> 17) | ((d1 >> 17) << 15));
    ga[i] = YA[(size_t)(d0 & 0x1FFFF) * 64 + l];
    gb[i] = YB[(size_t)(d1 & 0x1FFFF) * 64 + l];
    gc[i] = YC[(size_t)vw[i] * 64 + l];
  }

  float lo = 0.f, hi = 0.f;
#pragma unroll
  for (int i = 0; i < 16; ++i) {
    if (t0 + i < T_TRIP) {
      const float gx = bflo(g2[i]), gy = bfhi(g2[i]), gz = bflo(g3[i]), gw4 = bfhi(g3[i]);
      float p0 = bflo(ga[i]) + bflo(gb[i]) + bflo(gc[i]) + bb0
               + gx * wd[0][0] + gy * wd[1][0] + gz * wd[2][0] + gw4 * wd[3][0];
      float p1 = bfhi(ga[i]) + bfhi(gb[i]) + bfhi(gc[i]) + bb1
               + gx * wd[0][1] + gy * wd[1][1] + gz * wd[2][1] + gw4 * wd[3][1];
      lo += p0 * __builtin_amdgcn_rcpf(1.f + __expf(-p0));
      hi += p1 * __builtin_amdgcn_rcpf(1.f + __expf(-p1));
    }
    bool flush;
    if (i == 15) flush = true; else flush = (vw[i + 1 < 16 ? i + 1 : 15] != vw[i]);
    if (flush) {
      u16* p = Hagg + (size_t)vw[i] * 128 + l * 2;
      u32 pk;
      asm("v_cvt_pk_bf16_f32 %0, %1, %2" : "=v"(pk) : "v"(lo), "v"(hi));
      asm volatile("global_atomic_pk_add_bf16 %0, %1, off" :: "v"(p), "v"(pk) : "memory");
      lo = 0.f; hi = 0.f;
    }
  }
}

// ================= pair2: agg = Hagg@W2 + cnt*b2; out = h + phi([H|agg]) =================
__global__ __launch_bounds__(256, 3) void k_pair2(
    const float* __restrict__ h_pair, const u16* __restrict__ H, const u16* __restrict__ Hagg,
    const int* __restrict__ cnt, const u16* __restrict__ W2T,
    const u16* __restrict__ PW1T, const u16* __restrict__ PW2T,
    const float* __restrict__ psi_b2, const float* __restrict__ b1, const float* __restrict__ b2,
    float* __restrict__ out) {
  __shared__ __align__(16) u16 xl[64 * X2STR];
  __shared__ __align__(16) u16 hl[64 * HSTR];
  u32* xl32 = reinterpret_cast<u32*>(xl);

  const int tid = threadIdx.x;
  const int r0 = blockIdx.x * 64;

  {
    const int row = tid >> 2, q = tid & 3;
    int rc = r0 + row; rc = (rc < NP) ? rc : (NP - 1);
    const u16x8* sh = reinterpret_cast<const u16x8*>(H + (size_t)rc * 128 + q * 32);
    const u16x8* sa = reinterpret_cast<const u16x8*>(Hagg + (size_t)rc * 128 + q * 32);
    u16x8* d1 = reinterpret_cast<u16x8*>(&xl[row * X2STR + q * 32]);
    u16x8* d2 = reinterpret_cast<u16x8*>(&hl[row * HSTR + q * 32]);
#pragma unroll
    for (int i = 0; i < 4; ++i) { d1[i] = sh[i]; d2[i] = sa[i]; }
  }
  __syncthreads();

  const int w = tid >> 6, l = tid & 63;
  const int lr = l & 15, lk = (l >> 4) << 3;
  const int n0 = w * 32 + lr;
  const int rowh = (l >> 4) << 2;

  // ---- front GEMM: agg = Hagg @ W2 + cnt*b2 -> xl cols 128..255 (bf16) ----
  {
    f32x4 acc[4][2] = {};
#pragma unroll
    for (int ks = 0; ks < 4; ++ks) {
      bf16x8 a[4], b[2];
#pragma unroll
      for (int rt = 0; rt < 4; ++rt)
        a[rt] = *reinterpret_cast<const bf16x8*>(&hl[(rt * 16 + lr) * HSTR + ks * 32 + lk]);
#pragma unroll
      for (int ct = 0; ct < 2; ++ct)
        b[ct] = *reinterpret_cast<const bf16x8*>(&W2T[(size_t)(n0 + ct * 16) * 128 + ks * 32 + lk]);
#pragma unroll
      for (int rt = 0; rt < 4; ++rt)
#pragma unroll
        for (int ct = 0; ct < 2; ++ct)
          acc[rt][ct] = MFMA16(a[rt], b[ct], acc[rt][ct]);
    }
    const float pb2v[2] = {psi_b2[n0], psi_b2[n0 + 16]};
#pragma unroll
    for (int rt = 0; rt < 4; ++rt)
#pragma unroll
      for (int j = 0; j < 4; ++j) {
        const int row = rt * 16 + rowh + j;
        int rc = r0 + row; rc = (rc < NP) ? rc : (NP - 1);
        const float cf = (float)cnt[rc];
        float v0 = acc[rt][0][j] + cf * pb2v[0];
        float v1 = acc[rt][1][j] + cf * pb2v[1];
        float x0 = __shfl_xor(v0, 1), x1 = __shfl_xor(v1, 1);
        const bool even = (l & 1) == 0;
        float lo = even ? v0 : x1, hi = even ? x0 : v1;
        const int dcol = even ? (n0 >> 1) : ((n0 + 15) >> 1);
        u32 pk;
        asm("v_cvt_pk_bf16_f32 %0, %1, %2" : "=v"(pk) : "v"(lo), "v"(hi));
        xl32[row * (X2STR / 2) + 64 + dcol] = pk;
      }
  }
  LGKM0();
  __syncthreads();

  // ---- phi GEMM1 (K=256) ----
  f32x4 acc[4][2] = {};
#pragma unroll 1
  for (int ks = 0; ks < 8; ++ks) {
    const int k0 = ks * 32;
    bf16x8 a[4], b[2];
#pragma unroll
    for (int rt = 0; rt < 4; ++rt)
      a[rt] = *reinterpret_cast<const bf16x8*>(&xl[(rt * 16 + lr) * X2STR + k0 + lk]);
#pragma unroll
    for (int ct = 0; ct < 2; ++ct)
      b[ct] = *reinterpret_cast<const bf16x8*>(&PW1T[(size_t)(n0 + ct * 16) * 256 + k0 + lk]);
#pragma unroll
    for (int rt = 0; rt < 4; ++rt)
#pragma unroll
      for (int ct = 0; ct < 2; ++ct)
        acc[rt][ct] = MFMA16(a[rt], b[ct], acc[rt][ct]);
  }

  {
    const float b1v0 = b1[n0], b1v1 = b1[n0 + 16];
#pragma unroll
    for (int rt = 0; rt < 4; ++rt)
#pragma unroll
      for (int ct = 0; ct < 2; ++ct) {
        const float bb = ct ? b1v1 : b1v0;
#pragma unroll
        for (int j = 0; j < 4; ++j) {
          float v = acc[rt][ct][j] + bb;
          v = v * __builtin_amdgcn_rcpf(1.f + __expf(-v));
          hl[(rt * 16 + rowh + j) * HSTR + n0 + ct * 16] = cvt1_pk(v);
        }
      }
  }
  __syncthreads();

  // ---- phi GEMM2 ----
  f32x4 acc2[4][2] = {};
#pragma unroll
  for (int ks = 0; ks < 4; ++ks) {
    const int k0 = ks * 32;
    bf16x8 a[4], b[2];
#pragma unroll
    for (int rt = 0; rt < 4; ++rt)
      a[rt] = *reinterpret_cast<const bf16x8*>(&hl[(rt * 16 + lr) * HSTR + k0 + lk]);
#pragma unroll
    for (int ct = 0; ct < 2; ++ct)
      b[ct] = *reinterpret_cast<const bf16x8*>(&PW2T[(size_t)(n0 + ct * 16) * 128 + k0 + lk]);
#pragma unroll
    for (int rt = 0; rt < 4; ++rt)
#pragma unroll
      for (int ct = 0; ct < 2; ++ct)
        acc2[rt][ct] = MFMA16(a[rt], b[ct], acc2[rt][ct]);
  }

  {
    const float b2v0 = b2[n0], b2v1 = b2[n0 + 16];
#pragma unroll
    for (int rt = 0; rt < 4; ++rt)
#pragma unroll
      for (int j = 0; j < 4; ++j) {
        const int row = rt * 16 + rowh + j;
        const int r = r0 + row;
        if (r < NP) {
          out[(size_t)r * 128 + n0]      = h_pair[(size_t)r * 128 + n0]      + acc2[rt][0][j] + b2v0;
          out[(size_t)r * 128 + n0 + 16] = h_pair[(size_t)r * 128 + n0 + 16] + acc2[rt][1][j] + b2v1;
        }
      }
  }
}

// ===================== R0 fallback (tiny ws) =====================
#define PSI_W1T_OFF 0
#define PSI_W2T_OFF 53248
#define PHI_W1T_OFF 69632
#define PHI_W2T_OFF 102400
#define WS_U16_TOTAL 118784
#define XSTR 424

__global__ void k_prep(const float* __restrict__ psi_w1, const float* __restrict__ psi_w2,
                       const float* __restrict__ phi_w1, const float* __restrict__ phi_w2,
                       u16* __restrict__ ws) {
  int i = blockIdx.x * 256 + threadIdx.x;
  if (i < 128 * 416) {
    int n = i / 416, k = i % 416;
    ws[PSI_W1T_OFF + i] = f2bf(k < 388 ? psi_w1[k * 128 + n] : 0.f);
    return;
  }
  i -= 128 * 416;
  if (i < 128 * 128) {
    int n = i / 128, k = i % 128;
    ws[PSI_W2T_OFF + i] = f2bf(psi_w2[k * 128 + n]);
    return;
  }
  i -= 128 * 128;
  if (i < 128 * 256) {
    int n = i / 256, k = i % 256;
    ws[PHI_W1T_OFF + i] = f2bf(phi_w1[k * 128 + n]);
    return;
  }
  i -= 128 * 256;
  if (i < 128 * 128) {
    int n = i / 128, k = i % 128;
    ws[PHI_W2T_OFF + i] = f2bf(phi_w2[k * 128 + n]);
  }
}

__global__ __launch_bounds__(256, 2) void k_triplet(
    const float* __restrict__ h_pair,
    const int* __restrict__ ivu, const int* __restrict__ iuw, const int* __restrict__ ivw,
    const float* __restrict__ geom,
    const u16* __restrict__ W1T, const u16* __restrict__ W2T,
    const float* __restrict__ b1, const float* __restrict__ b2,
    float* __restrict__ agg) {
  __shared__ __align__(16) u16 xl[64 * XSTR];
  __shared__ __align__(16) u16 hl[64 * HSTR];
  __shared__ int svw[64];

  const int tid = threadIdx.x;
  const int t0 = blockIdx.x * 64;

  {
    const int row = tid >> 2, q = tid & 3;
    const int t = t0 + row;
    const int tc = (t < T_TRIP) ? t : (T_TRIP - 1);
    if (q == 0) svw[row] = (t < T_TRIP) ? ivw[tc] : -1;
    int idx[3];
    idx[0] = ivu[tc]; idx[1] = iuw[tc]; idx[2] = ivw[tc];
#pragma unroll
    for (int s = 0; s < 3; ++s) {
      const float4* src = reinterpret_cast<const float4*>(h_pair + (size_t)idx[s] * 128 + q * 32);
      u16* dst = &xl[row * XSTR + s * 128 + q * 32];
#pragma unroll
      for (int i = 0; i < 8; ++i)
        *reinterpret_cast<ushort4*>(dst + i * 4) = cvt4(src[i]);
    }
  }
  if (tid < 64) {
    const int t = t0 + tid;
    const int tc = (t < T_TRIP) ? t : (T_TRIP - 1);
    const float4 g = reinterpret_cast<const float4*>(geom)[tc];
    u16* dst = &xl[tid * XSTR + 384];
    *reinterpret_cast<ushort4*>(dst) = cvt4(g);
    ushort4 z = {0, 0, 0, 0};
#pragma unroll
    for (int i = 1; i < 8; ++i) *reinterpret_cast<ushort4*>(dst + i * 4) = z;
  }
  __syncthreads();

  const int w = tid >> 6;
  const int l = tid & 63;
  const int lr = l & 15;
  const int lk = (l >> 4) << 3;
  const int n0 = w * 32 + lr;
  const int rowh = (l >> 4) << 2;

  f32x4 acc[4][2] = {};
#pragma unroll 1
  for (int ks = 0; ks < 13; ++ks) {
    const int k0 = ks * 32;
    bf16x8 a[4], b[2];
#pragma unroll
    for (int rt = 0; rt < 4; ++rt)
      a[rt] = *reinterpret_cast<const bf16x8*>(&xl[(rt * 16 + lr) * XSTR + k0 + lk]);
#pragma unroll
    for (int ct = 0; ct < 2; ++ct)
      b[ct] = *reinterpret_cast<const bf16x8*>(&W1T[(size_t)(n0 + ct * 16) * 416 + k0 + lk]);
#pragma unroll
    for (int rt = 0; rt < 4; ++rt)
#pragma unroll
      for (int ct = 0; ct < 2; ++ct)
        acc[rt][ct] = MFMA16(a[rt], b[ct], acc[rt][ct]);
  }

  {
    const float b1v0 = b1[n0], b1v1 = b1[n0 + 16];
#pragma unroll
    for (int rt = 0; rt < 4; ++rt)
#pragma unroll
      for (int ct = 0; ct < 2; ++ct) {
        const float bb = ct ? b1v1 : b1v0;
#pragma unroll
        for (int j = 0; j < 4; ++j) {
          float v = acc[rt][ct][j] + bb;
          v = v / (1.f + __expf(-v));
          hl[(rt * 16 + rowh + j) * HSTR + n0 + ct * 16] = f2bf(v);
        }
      }
  }
  __syncthreads();

  f32x4 acc2[4][2] = {};
#pragma unroll
  for (int ks = 0; ks < 4; ++ks) {
    const int k0 = ks * 32;
    bf16x8 a[4], b[2];
#pragma unroll
    for (int rt = 0; rt < 4; ++rt)
      a[rt] = *reinterpret_cast<const bf16x8*>(&hl[(rt * 16 + lr) * HSTR + k0 + lk]);
#pragma unroll
    for (int ct = 0; ct < 2; ++ct)
      b[ct] = *reinterpret_cast<const bf16x8*>(&W2T[(size_t)(n0 + ct * 16) * 128 + k0 + lk]);
#pragma unroll
    for (int rt = 0; rt < 4; ++rt)
#pragma unroll
      for (int ct = 0; ct < 2; ++ct)
        acc2[rt][ct] = MFMA16(a[rt], b[ct], acc2[rt][ct]);
  }

  {
    const float b2v0 = b2[n0], b2v1 = b2[n0 + 16];
#pragma unroll
    for (int rt = 0; rt < 4; ++rt)
#pragma unroll
      for (int j = 0; j < 4; ++j) {
        const int row = rt * 16 + rowh + j;
        const int dst = svw[row];
        if (dst >= 0) {
          unsafeAtomicAdd(&agg[(size_t)dst * 128 + n0], acc2[rt][0][j] + b2v0);
          unsafeAtomicAdd(&agg[(size_t)dst * 128 + n0 + 16], acc2[rt][1][j] + b2v1);
        }
      }
  }
}

__global__ __launch_bounds__(256, 2) void k_pair(
    const float* __restrict__ h_pair,
    const u16* __restrict__ W1T, const u16* __restrict__ W2T,
    const float* __restrict__ b1, const float* __restrict__ b2,
    float* __restrict__ out) {
  __shared__ __align__(16) u16 xl[64 * X2STR];
  __shared__ __align__(16) u16 hl[64 * HSTR];

  const int tid = threadIdx.x;
  const int r0 = blockIdx.x * 64;

  {
    const int row = tid >> 2, q = tid & 3;
    const int r = r0 + row;
    const int rc = (r < NP) ? r : (NP - 1);
    const float4* s1 = reinterpret_cast<const float4*>(h_pair + (size_t)rc * 128 + q * 32);
    const float4* s2 = reinterpret_cast<const float4*>(out + (size_t)rc * 128 + q * 32);
    u16* d1 = &xl[row * X2STR + q * 32];
    u16* d2 = &xl[row * X2STR + 128 + q * 32];
#pragma unroll
    for (int i = 0; i < 8; ++i) {
      *reinterpret_cast<ushort4*>(d1 + i * 4) = cvt4(s1[i]);
      *reinterpret_cast<ushort4*>(d2 + i * 4) = cvt4(s2[i]);
    }
  }
  __syncthreads();

  const int w = tid >> 6;
  const int l = tid & 63;
  const int lr = l & 15;
  const int lk = (l >> 4) << 3;
  const int n0 = w * 32 + lr;
  const int rowh = (l >> 4) << 2;

  f32x4 acc[4][2] = {};
#pragma unroll 1
  for (int ks = 0; ks < 8; ++ks) {
    const int k0 = ks * 32;
    bf16x8 a[4], b[2];
#pragma unroll
    for (int rt = 0; rt < 4; ++rt)
      a[rt] = *reinterpret_cast<const bf16x8*>(&xl[(rt * 16 + lr) * X2STR + k0 + lk]);
#pragma unroll
    for (int ct = 0; ct < 2; ++ct)
      b[ct] = *reinterpret_cast<const bf16x8*>(&W1T[(size_t)(n0 + ct * 16) * 256 + k0 + lk]);
#pragma unroll
    for (int rt = 0; rt < 4; ++rt)
#pragma unroll
      for (int ct = 0; ct < 2; ++ct)
        acc[rt][ct] = MFMA16(a[rt], b[ct], acc[rt][ct]);
  }

  {
    const float b1v0 = b1[n0], b1v1 = b1[n0 + 16];
#pragma unroll
    for (int rt = 0; rt < 4; ++rt)
#pragma unroll
      for (int ct = 0; ct < 2; ++ct) {
        const float bb = ct ? b1v1 : b1v0;
#pragma unroll
        for (int j = 0; j < 4; ++j) {
          float v = acc[rt][ct][j] + bb;
          v = v / (1.f + __expf(-v));
          hl[(rt * 16 + rowh + j) * HSTR + n0 + ct * 16] = f2bf(v);
        }
      }
  }
  __syncthreads();

  f32x4 acc2[4][2] = {};
#pragma unroll
  for (int ks = 0; ks < 4; ++ks) {
    const int k0 = ks * 32;
    bf16x8 a[4], b[2];
#pragma unroll
    for (int rt = 0; rt < 4; ++rt)
      a[rt] = *reinterpret_cast<const bf16x8*>(&hl[(rt * 16 + lr) * HSTR + k0 + lk]);
#pragma unroll
    for (int ct = 0; ct < 2; ++ct)
      b[ct] = *reinterpret_cast<const bf16x8*>(&W2T[(size_t)(n0 + ct * 16) * 128 + k0 + lk]);
#pragma unroll
    for (int rt = 0; rt < 4; ++rt)
#pragma unroll
      for (int ct = 0; ct < 2; ++ct)
        acc2[rt][ct] = MFMA16(a[rt], b[ct], acc2[rt][ct]);
  }

  {
    const float b2v0 = b2[n0], b2v1 = b2[n0 + 16];
#pragma unroll
    for (int rt = 0; rt < 4; ++rt)
#pragma unroll
      for (int j = 0; j < 4; ++j) {
        const int row = rt * 16 + rowh + j;
        const int r = r0 + row;
        if (r < NP) {
          out[(size_t)r * 128 + n0]      = h_pair[(size_t)r * 128 + n0]      + acc2[rt][0][j] + b2v0;
          out[(size_t)r * 128 + n0 + 16] = h_pair[(size_t)r * 128 + n0 + 16] + acc2[rt][1][j] + b2v1;
        }
      }
  }
}

extern "C" void kernel_launch(void* const* d_in, const int* in_sizes, int n_in,
                              void* d_out, int out_size, void* d_ws, size_t ws_size,
                              hipStream_t stream) {
  const float* h_pair = (const float*)d_in[0];
  const int* ivu = (const int*)d_in[1];
  const int* iuw = (const int*)d_in[2];
  const int* ivw = (const int*)d_in[3];
  const float* geom = (const float*)d_in[4];
  const float* psi_w1 = (const float*)d_in[5];
  const float* psi_b1 = (const float*)d_in[6];
  const float* psi_w2 = (const float*)d_in[7];
  const float* psi_b2 = (const float*)d_in[8];
  const float* phi_w1 = (const float*)d_in[9];
  const float* phi_b1 = (const float*)d_in[10];
  const float* phi_w2 = (const float*)d_in[11];
  const float* phi_b2 = (const float*)d_in[12];

  float* out = (float*)d_out;
  u16* ws = (u16*)d_ws;
  char* wsb = (char*)d_ws;

  if (ws_size >= WS_S3) {
    int*  cnt    = (int*)(wsb + SB_CNT2);
    int*  cursor = (int*)(wsb + SB_CURSOR2);
    int*  bsum   = (int*)(wsb + SB_BSUM2);
    int4* trip   = (int4*)(wsb + SB_TRIP);
    u32*  YA     = (u32*)(wsb + SB_YA);
    u32*  YB     = (u32*)(wsb + SB_YB);
    u32*  YC     = (u32*)(wsb + SB_YC);

    hipMemsetAsync(cnt, 0, NP * sizeof(int), stream);
    k_pre3<<<5529, 256, 0, stream>>>(psi_w1, psi_w2, phi_w1, phi_w2, ivw, ws, cnt);
    k_scan1<<<98, 1024, 0, stream>>>(cnt, cursor, bsum);
    k_scan2<<<1, 128, 0, stream>>>(bsum);
    k_perm_pack<<<1954, 256, 0, stream>>>(ivu, iuw, ivw, geom, cursor, bsum, trip);
    k_proj<<<1563, 256, 0, stream>>>(h_pair, ws + FP_W1A, ws + FP_W1B, ws + FP_W1C,
                                     ws + FP_H, YA, YB, YC);
    k_gsilu<<<(NBATCH + 3) / 4, 256, 0, stream>>>(
        YA, YB, YC, (const u32*)trip,
        reinterpret_cast<const float*>(ws + FP_W1D), psi_b1, ws + FP_AGG);
    k_pair2<<<1563, 256, 0, stream>>>(
        h_pair, ws + FP_H, ws + FP_AGG, cnt, ws + FP_W2,
        ws + FP_PW1, ws + FP_PW2, psi_b2, phi_b1, phi_b2, out);
  } else {
    // ---------- R0 fallback ----------
    hipMemsetAsync(d_out, 0, (size_t)out_size * sizeof(float), stream);
    k_prep<<<(WS_U16_TOTAL + 255) / 256, 256, 0, stream>>>(psi_w1, psi_w2, phi_w1, phi_w2, ws);
    k_triplet<<<(T_TRIP + 63) / 64, 256, 0, stream>>>(
        h_pair, ivu, iuw, ivw, geom,
        ws + PSI_W1T_OFF, ws + PSI_W2T_OFF, psi_b1, psi_b2, out);
    k_pair<<<(NP + 63) / 64, 256, 0, stream>>>(
        h_pair, ws + PHI_W1T_OFF, ws + PHI_W2T_OFF, phi_b1, phi_b2, out);
  }
}

// Round 10
// 249.899 us; speedup vs baseline: 1.1840x; 1.1523x over previous
//
#include <hip/hip_runtime.h>
#include <hip/hip_bf16.h>

#define T_TRIP 500000
#define NP     100000
#define NPAD   500032
#define NBATCH 31252   // NPAD/16

typedef float f32x4 __attribute__((ext_vector_type(4)));
typedef __bf16 bf16x8 __attribute__((ext_vector_type(8)));
typedef unsigned short u16;
typedef unsigned short u16x8 __attribute__((ext_vector_type(8)));
typedef unsigned int u32;

__device__ __forceinline__ u16 f2bf(float f) {
  union { float f; unsigned u; } v; v.f = f;
  unsigned r = v.u + 0x7fffu + ((v.u >> 16) & 1u);
  return (u16)(r >> 16);
}

__device__ __forceinline__ ushort4 cvt4(float4 v) {
  ushort4 o; o.x = f2bf(v.x); o.y = f2bf(v.y); o.z = f2bf(v.z); o.w = f2bf(v.w);
  return o;
}

__device__ __forceinline__ u16 cvt1_pk(float v) {
  unsigned r;
  asm("v_cvt_pk_bf16_f32 %0, %1, %1" : "=v"(r) : "v"(v));
  return (u16)r;
}

__device__ __forceinline__ float bflo(u32 d) {
  union { u32 u; float f; } v; v.u = d << 16; return v.f;
}
__device__ __forceinline__ float bfhi(u32 d) {
  union { u32 u; float f; } v; v.u = d & 0xffff0000u; return v.f;
}

#define MFMA16(a, b, c) __builtin_amdgcn_mfma_f32_16x16x32_bf16((a), (b), (c), 0, 0, 0)
#define LGKM0()   asm volatile("s_waitcnt lgkmcnt(0)" ::: "memory")

// =================== ws layout ===================
#define FP_W1A   0u
#define FP_W1B   16384u
#define FP_W1C   32768u
#define FP_W2    49152u
#define FP_PW1   65536u
#define FP_PW2   98304u
#define FP_W1D   114688u    // f32 [4][128]
#define FP_H     131072u    // h_pair bf16 [NP][128]
#define FP_AGG   12931072u  // Hagg bf16 [NP][128]
#define SB_CNT2    51462144ull
#define SB_CURSOR2 51862144ull
#define SB_BSUM2   52262144ull
#define SB_TRIP    52262656ull          // 16B packed AoS per triplet
#define SB_YA      60263168ull          // u32 [NP][64]
#define SB_YB      85863168ull
#define SB_YC     111463168ull
#define WS_S3     137063168ull

#define HSTR   136
#define X2STR  264

// ---------------- pre: weights prep + zero Hagg + histogram ----------------
__global__ void k_pre3(const float* __restrict__ psi_w1, const float* __restrict__ psi_w2,
                       const float* __restrict__ phi_w1, const float* __restrict__ phi_w2,
                       const int* __restrict__ ivw,
                       u16* __restrict__ ws, int* __restrict__ cnt) {
  const int b = blockIdx.x;
  if (b < 450) {
    int i = b * 256 + threadIdx.x;
    if (i < 49152) {
      int s = i / 16384, r = i % 16384;
      int n = r / 128, k = r % 128;
      ws[FP_W1A + i] = f2bf(psi_w1[(s * 128 + k) * 128 + n]);
      return;
    }
    i -= 49152;
    if (i < 16384) {
      int n = i / 128, k = i % 128;
      ws[FP_W2 + i] = f2bf(psi_w2[k * 128 + n]);
      return;
    }
    i -= 16384;
    if (i < 32768) {
      int n = i / 256, k = i % 256;
      ws[FP_PW1 + i] = f2bf(phi_w1[k * 128 + n]);
      return;
    }
    i -= 32768;
    if (i < 16384) {
      int n = i / 128, k = i % 128;
      ws[FP_PW2 + i] = f2bf(phi_w2[k * 128 + n]);
      return;
    }
    i -= 16384;
    if (i < 512) {
      int k = i / 128, n = i % 128;
      reinterpret_cast<float*>(ws + FP_W1D)[i] = psi_w1[(384 + k) * 128 + n];
    }
  } else if (b < 3575) {
    const size_t i = (size_t)((b - 450) * 256 + threadIdx.x) * 16;
    ushort4 z = {0, 0, 0, 0};
    u16* d = ws + FP_AGG + i;
#pragma unroll
    for (int k = 0; k < 4; ++k) *reinterpret_cast<ushort4*>(d + k * 4) = z;
  } else {
    int i = (b - 3575) * 256 + threadIdx.x;
    if (i < T_TRIP) atomicAdd(&cnt[ivw[i]], 1);
  }
}

// ================= scan =================
__global__ __launch_bounds__(1024) void k_scan1(const int* __restrict__ cnt,
                                                int* __restrict__ cursor, int* __restrict__ bsum) {
  __shared__ int wsum[16];
  const int idx = blockIdx.x * 1024 + threadIdx.x;
  const int lane = threadIdx.x & 63, wid = threadIdx.x >> 6;
  int v = (idx < NP) ? cnt[idx] : 0;
  int x = v;
#pragma unroll
  for (int off = 1; off < 64; off <<= 1) {
    int n = __shfl_up(x, off);
    if (lane >= off) x += n;
  }
  if (lane == 63) wsum[wid] = x;
  __syncthreads();
  if (threadIdx.x < 16) {
    int s = wsum[threadIdx.x];
#pragma unroll
    for (int off = 1; off < 16; off <<= 1) {
      int n = __shfl_up(s, off);
      if (threadIdx.x >= off) s += n;
    }
    wsum[threadIdx.x] = s;
  }
  __syncthreads();
  const int base = wid ? wsum[wid - 1] : 0;
  if (idx < NP) cursor[idx] = base + x - v;
  if (threadIdx.x == 1023) bsum[blockIdx.x] = base + x;
}

__global__ void k_scan2(int* __restrict__ bsum) {
  __shared__ int s[128];
  const int t = threadIdx.x;
  int v = (t < 98) ? bsum[t] : 0;
  s[t] = v; __syncthreads();
#pragma unroll
  for (int off = 1; off < 128; off <<= 1) {
    int a = (t >= off) ? s[t - off] : 0;
    __syncthreads();
    s[t] += a;
    __syncthreads();
  }
  if (t < 98) bsum[t] = s[t] - v;
}

// ================= permute -> 16B packed AoS =================
__global__ void k_perm_pack(const int* __restrict__ ivu, const int* __restrict__ iuw,
                            const int* __restrict__ ivw, const float* __restrict__ geom,
                            int* __restrict__ cursor, const int* __restrict__ bsum,
                            int4* __restrict__ trip) {
  int i = blockIdx.x * 256 + threadIdx.x;
  if (i < T_TRIP) {
    int v = ivw[i];
    int pos = atomicAdd(&cursor[v], 1) + bsum[v >> 10];
    float4 g = reinterpret_cast<const float4*>(geom)[i];
    u32 pk0, pk1;
    asm("v_cvt_pk_bf16_f32 %0, %1, %2" : "=v"(pk0) : "v"(g.x), "v"(g.y));
    asm("v_cvt_pk_bf16_f32 %0, %1, %2" : "=v"(pk1) : "v"(g.z), "v"(g.w));
    int4 rec;
    rec.x = ivu[i] | ((v & 0x7fff) << 17);
    rec.y = iuw[i] | ((v >> 15) << 17);
    rec.z = (int)pk0;
    rec.w = (int)pk1;
    trip[pos] = rec;
  } else if (i < NPAD) {
    int4 z = {0, 0, 0, 0};
    trip[i] = z;
  }
}

// ================= proj: h -> H bf16, Y_{a,b,c} = H @ W1{a,b,c}^T =================
__global__ __launch_bounds__(256, 4) void k_proj(
    const float* __restrict__ h, const u16* __restrict__ W1A, const u16* __restrict__ W1B,
    const u16* __restrict__ W1C, u16* __restrict__ H,
    u32* __restrict__ YA, u32* __restrict__ YB, u32* __restrict__ YC) {
  __shared__ __align__(16) u16 xs[64 * 132];
  const int tid = threadIdx.x;
  const int r0 = blockIdx.x * 64;
  {
    const int row = tid >> 2, q = tid & 3;
    int rc = r0 + row; rc = (rc < NP) ? rc : (NP - 1);
    const float4* src = reinterpret_cast<const float4*>(h + (size_t)rc * 128 + q * 32);
    u16* ldst = &xs[row * 132 + q * 32];
    u16* gdst = H + (size_t)rc * 128 + q * 32;
#pragma unroll
    for (int i = 0; i < 8; ++i) {
      ushort4 c = cvt4(src[i]);
      *reinterpret_cast<ushort4*>(ldst + i * 4) = c;
      *reinterpret_cast<ushort4*>(gdst + i * 4) = c;
    }
  }
  __syncthreads();
  const int w = tid >> 6, l = tid & 63;
  const int lr = l & 15, lk = (l >> 4) << 3;
  const int n0 = w * 32 + lr;
  const int rowh = (l >> 4) << 2;

  const u16* WT[3] = {W1A, W1B, W1C};
  u32* YT[3] = {YA, YB, YC};
#pragma unroll
  for (int s = 0; s < 3; ++s) {
    f32x4 acc[4][2] = {};
#pragma unroll
    for (int ks = 0; ks < 4; ++ks) {
      bf16x8 a[4], b[2];
#pragma unroll
      for (int rt = 0; rt < 4; ++rt)
        a[rt] = *reinterpret_cast<const bf16x8*>(&xs[(rt * 16 + lr) * 132 + ks * 32 + lk]);
#pragma unroll
      for (int ct = 0; ct < 2; ++ct)
        b[ct] = *reinterpret_cast<const bf16x8*>(&WT[s][(size_t)(n0 + ct * 16) * 128 + ks * 32 + lk]);
#pragma unroll
      for (int rt = 0; rt < 4; ++rt)
#pragma unroll
        for (int ct = 0; ct < 2; ++ct)
          acc[rt][ct] = MFMA16(a[rt], b[ct], acc[rt][ct]);
    }
#pragma unroll
    for (int rt = 0; rt < 4; ++rt)
#pragma unroll
      for (int j = 0; j < 4; ++j) {
        const int row = rt * 16 + rowh + j;
        float v0 = acc[rt][0][j], v1 = acc[rt][1][j];
        float x0 = __shfl_xor(v0, 1), x1 = __shfl_xor(v1, 1);
        const bool even = (l & 1) == 0;
        float lo = even ? v0 : x1, hi = even ? x0 : v1;
        const int dcol = even ? (n0 >> 1) : ((n0 + 15) >> 1);
        if (r0 + row < NP) {
          u32 pk;
          asm("v_cvt_pk_bf16_f32 %0, %1, %2" : "=v"(pk) : "v"(lo), "v"(hi));
          YT[s][(size_t)(r0 + row) * 64 + dcol] = pk;
        }
      }
  }
}

// ================= gsilu2: gather + silu + run-reduce; plain stores for interior runs =================
// Wave = 16 sorted triplets; lane l = cols 2l,2l+1. YC hoisted per run.
// Atomics ONLY for runs continuing across batch boundaries; all others plain 256B store.
__global__ void k_gsilu2(
    const u32* __restrict__ YA, const u32* __restrict__ YB, const u32* __restrict__ YC,
    const u32* __restrict__ tripw, const float* __restrict__ w1dF,
    const float* __restrict__ b1, u16* __restrict__ Hagg) {
  const int w = threadIdx.x >> 6, l = threadIdx.x & 63;
  const int batch = blockIdx.x * 4 + w;
  if (batch >= NBATCH) return;
  const int t0 = batch * 16;

  const u32 aos = tripw[(size_t)batch * 64 + l];

  float wd[4][2];
#pragma unroll
  for (int k = 0; k < 4; ++k) {
    wd[k][0] = w1dF[k * 128 + 2 * l];
    wd[k][1] = w1dF[k * 128 + 2 * l + 1];
  }
  const float bb0 = b1[2 * l], bb1 = b1[2 * l + 1];

  int vw[16];
  u32 g2[16], g3[16], ga[16], gb[16];
#pragma unroll
  for (int i = 0; i < 16; ++i) {
    const u32 d0 = (u32)__shfl((int)aos, i * 4);
    const u32 d1 = (u32)__shfl((int)aos, i * 4 + 1);
    g2[i] = (u32)__shfl((int)aos, i * 4 + 2);
    g3[i] = (u32)__shfl((int)aos, i * 4 + 3);
    vw[i] = (int)((d0 >> 17) | ((d1 >> 17) << 15));
    ga[i] = YA[(size_t)(d0 & 0x1FFFF) * 64 + l];
    gb[i] = YB[(size_t)(d1 & 0x1FFFF) * 64 + l];
  }

  // neighbor vw for continuation detection (uniform-address loads, broadcast)
  int prevVw = -1, nextVw = -1;
  if (t0 > 0) {
    u32 pd0 = tripw[(size_t)(t0 - 1) * 4];
    u32 pd1 = tripw[(size_t)(t0 - 1) * 4 + 1];
    prevVw = (int)((pd0 >> 17) | ((pd1 >> 17) << 15));
  }
  if (t0 + 16 < T_TRIP) {
    u32 nd0 = tripw[(size_t)(t0 + 16) * 4];
    u32 nd1 = tripw[(size_t)(t0 + 16) * 4 + 1];
    nextVw = (int)((nd0 >> 17) | ((nd1 >> 17) << 15));
  }

  float lo = 0.f, hi = 0.f;
  u32 gcc = 0;
  int istart = 0;
#pragma unroll
  for (int i = 0; i < 16; ++i) {
    const bool runStart = (i == 0) || (vw[i] != vw[i - 1]);
    if (runStart) {
      istart = i;
      gcc = YC[(size_t)vw[i] * 64 + l];      // hoisted: one YC row read per run
    }
    if (t0 + i < T_TRIP) {
      const float gx = bflo(g2[i]), gy = bfhi(g2[i]), gz = bflo(g3[i]), gw4 = bfhi(g3[i]);
      float p0 = bflo(ga[i]) + bflo(gb[i]) + bflo(gcc) + bb0
               + gx * wd[0][0] + gy * wd[1][0] + gz * wd[2][0] + gw4 * wd[3][0];
      float p1 = bfhi(ga[i]) + bfhi(gb[i]) + bfhi(gcc) + bb1
               + gx * wd[0][1] + gy * wd[1][1] + gz * wd[2][1] + gw4 * wd[3][1];
      lo += p0 * __builtin_amdgcn_rcpf(1.f + __expf(-p0));
      hi += p1 * __builtin_amdgcn_rcpf(1.f + __expf(-p1));
    }
    const bool runEnd = (i == 15) || (vw[i + 1 < 16 ? i + 1 : 15] != vw[i]) || (i == 15);
    bool doflush;
    if (i == 15) doflush = true;
    else doflush = (vw[i + 1] != vw[i]);
    (void)runEnd;
    if (doflush && (t0 + istart < T_TRIP)) {
      const bool contL = (istart == 0) && (vw[i] == prevVw);
      const bool contR = (i == 15) && (vw[i] == nextVw);
      u16* p = Hagg + (size_t)vw[i] * 128 + l * 2;
      u32 pk;
      asm("v_cvt_pk_bf16_f32 %0, %1, %2" : "=v"(pk) : "v"(lo), "v"(hi));
      if (contL || contR) {
        asm volatile("global_atomic_pk_add_bf16 %0, %1, off" :: "v"(p), "v"(pk) : "memory");
      } else {
        *reinterpret_cast<u32*>(p) = pk;     // interior run: plain store, no RMW
      }
      lo = 0.f; hi = 0.f;
    }
    if (doflush) { /* next run state reset handled by runStart */ }
  }
}

// ================= pair2: agg = Hagg@W2 + cnt*b2; out = h + phi([H|agg]) =================
__global__ __launch_bounds__(256, 3) void k_pair2(
    const float* __restrict__ h_pair, const u16* __restrict__ H, const u16* __restrict__ Hagg,
    const int* __restrict__ cnt, const u16* __restrict__ W2T,
    const u16* __restrict__ PW1T, const u16* __restrict__ PW2T,
    const float* __restrict__ psi_b2, const float* __restrict__ b1, const float* __restrict__ b2,
    float* __restrict__ out) {
  __shared__ __align__(16) u16 xl[64 * X2STR];
  __shared__ __align__(16) u16 hl[64 * HSTR];
  u32* xl32 = reinterpret_cast<u32*>(xl);

  const int tid = threadIdx.x;
  const int r0 = blockIdx.x * 64;

  {
    const int row = tid >> 2, q = tid & 3;
    int rc = r0 + row; rc = (rc < NP) ? rc : (NP - 1);
    const u16x8* sh = reinterpret_cast<const u16x8*>(H + (size_t)rc * 128 + q * 32);
    const u16x8* sa = reinterpret_cast<const u16x8*>(Hagg + (size_t)rc * 128 + q * 32);
    u16x8* d1 = reinterpret_cast<u16x8*>(&xl[row * X2STR + q * 32]);
    u16x8* d2 = reinterpret_cast<u16x8*>(&hl[row * HSTR + q * 32]);
#pragma unroll
    for (int i = 0; i < 4; ++i) { d1[i] = sh[i]; d2[i] = sa[i]; }
  }
  __syncthreads();

  const int w = tid >> 6, l = tid & 63;
  const int lr = l & 15, lk = (l >> 4) << 3;
  const int n0 = w * 32 + lr;
  const int rowh = (l >> 4) << 2;

  // ---- front GEMM: agg = Hagg @ W2 + cnt*psi_b2 -> xl cols 128..255 ----
  {
    f32x4 acc[4][2] = {};
#pragma unroll
    for (int ks = 0; ks < 4; ++ks) {
      bf16x8 a[4], b[2];
#pragma unroll
      for (int rt = 0; rt < 4; ++rt)
        a[rt] = *reinterpret_cast<const bf16x8*>(&hl[(rt * 16 + lr) * HSTR + ks * 32 + lk]);
#pragma unroll
      for (int ct = 0; ct < 2; ++ct)
        b[ct] = *reinterpret_cast<const bf16x8*>(&W2T[(size_t)(n0 + ct * 16) * 128 + ks * 32 + lk]);
#pragma unroll
      for (int rt = 0; rt < 4; ++rt)
#pragma unroll
        for (int ct = 0; ct < 2; ++ct)
          acc[rt][ct] = MFMA16(a[rt], b[ct], acc[rt][ct]);
    }
    const float pb2v[2] = {psi_b2[n0], psi_b2[n0 + 16]};
#pragma unroll
    for (int rt = 0; rt < 4; ++rt)
#pragma unroll
      for (int j = 0; j < 4; ++j) {
        const int row = rt * 16 + rowh + j;
        int rc = r0 + row; rc = (rc < NP) ? rc : (NP - 1);
        const float cf = (float)cnt[rc];
        float v0 = acc[rt][0][j] + cf * pb2v[0];
        float v1 = acc[rt][1][j] + cf * pb2v[1];
        float x0 = __shfl_xor(v0, 1), x1 = __shfl_xor(v1, 1);
        const bool even = (l & 1) == 0;
        float lo = even ? v0 : x1, hi = even ? x0 : v1;
        const int dcol = even ? (n0 >> 1) : ((n0 + 15) >> 1);
        u32 pk;
        asm("v_cvt_pk_bf16_f32 %0, %1, %2" : "=v"(pk) : "v"(lo), "v"(hi));
        xl32[row * (X2STR / 2) + 64 + dcol] = pk;
      }
  }
  LGKM0();
  __syncthreads();

  // ---- phi GEMM1 (K=256) ----
  f32x4 acc[4][2] = {};
#pragma unroll 1
  for (int ks = 0; ks < 8; ++ks) {
    const int k0 = ks * 32;
    bf16x8 a[4], b[2];
#pragma unroll
    for (int rt = 0; rt < 4; ++rt)
      a[rt] = *reinterpret_cast<const bf16x8*>(&xl[(rt * 16 + lr) * X2STR + k0 + lk]);
#pragma unroll
    for (int ct = 0; ct < 2; ++ct)
      b[ct] = *reinterpret_cast<const bf16x8*>(&PW1T[(size_t)(n0 + ct * 16) * 256 + k0 + lk]);
#pragma unroll
    for (int rt = 0; rt < 4; ++rt)
#pragma unroll
      for (int ct = 0; ct < 2; ++ct)
        acc[rt][ct] = MFMA16(a[rt], b[ct], acc[rt][ct]);
  }

  {
    const float b1v0 = b1[n0], b1v1 = b1[n0 + 16];
#pragma unroll
    for (int rt = 0; rt < 4; ++rt)
#pragma unroll
      for (int ct = 0; ct < 2; ++ct) {
        const float bb = ct ? b1v1 : b1v0;
#pragma unroll
        for (int j = 0; j < 4; ++j) {
          float v = acc[rt][ct][j] + bb;
          v = v * __builtin_amdgcn_rcpf(1.f + __expf(-v));
          hl[(rt * 16 + rowh + j) * HSTR + n0 + ct * 16] = cvt1_pk(v);
        }
      }
  }
  __syncthreads();

  // ---- phi GEMM2 ----
  f32x4 acc2[4][2] = {};
#pragma unroll
  for (int ks = 0; ks < 4; ++ks) {
    const int k0 = ks * 32;
    bf16x8 a[4], b[2];
#pragma unroll
    for (int rt = 0; rt < 4; ++rt)
      a[rt] = *reinterpret_cast<const bf16x8*>(&hl[(rt * 16 + lr) * HSTR + k0 + lk]);
#pragma unroll
    for (int ct = 0; ct < 2; ++ct)
      b[ct] = *reinterpret_cast<const bf16x8*>(&PW2T[(size_t)(n0 + ct * 16) * 128 + k0 + lk]);
#pragma unroll
    for (int rt = 0; rt < 4; ++rt)
#pragma unroll
      for (int ct = 0; ct < 2; ++ct)
        acc2[rt][ct] = MFMA16(a[rt], b[ct], acc2[rt][ct]);
  }

  {
    const float b2v0 = b2[n0], b2v1 = b2[n0 + 16];
#pragma unroll
    for (int rt = 0; rt < 4; ++rt)
#pragma unroll
      for (int j = 0; j < 4; ++j) {
        const int row = rt * 16 + rowh + j;
        const int r = r0 + row;
        if (r < NP) {
          out[(size_t)r * 128 + n0]      = h_pair[(size_t)r * 128 + n0]      + acc2[rt][0][j] + b2v0;
          out[(size_t)r * 128 + n0 + 16] = h_pair[(size_t)r * 128 + n0 + 16] + acc2[rt][1][j] + b2v1;
        }
      }
  }
}

// ===================== R0 fallback (tiny ws) =====================
#define PSI_W1T_OFF 0
#define PSI_W2T_OFF 53248
#define PHI_W1T_OFF 69632
#define PHI_W2T_OFF 102400
#define WS_U16_TOTAL 118784
#define XSTR 424

__global__ void k_prep(const float* __restrict__ psi_w1, const float* __restrict__ psi_w2,
                       const float* __restrict__ phi_w1, const float* __restrict__ phi_w2,
                       u16* __restrict__ ws) {
  int i = blockIdx.x * 256 + threadIdx.x;
  if (i < 128 * 416) {
    int n = i / 416, k = i % 416;
    ws[PSI_W1T_OFF + i] = f2bf(k < 388 ? psi_w1[k * 128 + n] : 0.f);
    return;
  }
  i -= 128 * 416;
  if (i < 128 * 128) {
    int n = i / 128, k = i % 128;
    ws[PSI_W2T_OFF + i] = f2bf(psi_w2[k * 128 + n]);
    return;
  }
  i -= 128 * 128;
  if (i < 128 * 256) {
    int n = i / 256, k = i % 256;
    ws[PHI_W1T_OFF + i] = f2bf(phi_w1[k * 128 + n]);
    return;
  }
  i -= 128 * 256;
  if (i < 128 * 128) {
    int n = i / 128, k = i % 128;
    ws[PHI_W2T_OFF + i] = f2bf(phi_w2[k * 128 + n]);
  }
}

__global__ __launch_bounds__(256, 2) void k_triplet(
    const float* __restrict__ h_pair,
    const int* __restrict__ ivu, const int* __restrict__ iuw, const int* __restrict__ ivw,
    const float* __restrict__ geom,
    const u16* __restrict__ W1T, const u16* __restrict__ W2T,
    const float* __restrict__ b1, const float* __restrict__ b2,
    float* __restrict__ agg) {
  __shared__ __align__(16) u16 xl[64 * XSTR];
  __shared__ __align__(16) u16 hl[64 * HSTR];
  __shared__ int svw[64];

  const int tid = threadIdx.x;
  const int t0 = blockIdx.x * 64;

  {
    const int row = tid >> 2, q = tid & 3;
    const int t = t0 + row;
    const int tc = (t < T_TRIP) ? t : (T_TRIP - 1);
    if (q == 0) svw[row] = (t < T_TRIP) ? ivw[tc] : -1;
    int idx[3];
    idx[0] = ivu[tc]; idx[1] = iuw[tc]; idx[2] = ivw[tc];
#pragma unroll
    for (int s = 0; s < 3; ++s) {
      const float4* src = reinterpret_cast<const float4*>(h_pair + (size_t)idx[s] * 128 + q * 32);
      u16* dst = &xl[row * XSTR + s * 128 + q * 32];
#pragma unroll
      for (int i = 0; i < 8; ++i)
        *reinterpret_cast<ushort4*>(dst + i * 4) = cvt4(src[i]);
    }
  }
  if (tid < 64) {
    const int t = t0 + tid;
    const int tc = (t < T_TRIP) ? t : (T_TRIP - 1);
    const float4 g = reinterpret_cast<const float4*>(geom)[tc];
    u16* dst = &xl[tid * XSTR + 384];
    *reinterpret_cast<ushort4*>(dst) = cvt4(g);
    ushort4 z = {0, 0, 0, 0};
#pragma unroll
    for (int i = 1; i < 8; ++i) *reinterpret_cast<ushort4*>(dst + i * 4) = z;
  }
  __syncthreads();

  const int w = tid >> 6;
  const int l = tid & 63;
  const int lr = l & 15;
  const int lk = (l >> 4) << 3;
  const int n0 = w * 32 + lr;
  const int rowh = (l >> 4) << 2;

  f32x4 acc[4][2] = {};
#pragma unroll 1
  for (int ks = 0; ks < 13; ++ks) {
    const int k0 = ks * 32;
    bf16x8 a[4], b[2];
#pragma unroll
    for (int rt = 0; rt < 4; ++rt)
      a[rt] = *reinterpret_cast<const bf16x8*>(&xl[(rt * 16 + lr) * XSTR + k0 + lk]);
#pragma unroll
    for (int ct = 0; ct < 2; ++ct)
      b[ct] = *reinterpret_cast<const bf16x8*>(&W1T[(size_t)(n0 + ct * 16) * 416 + k0 + lk]);
#pragma unroll
    for (int rt = 0; rt < 4; ++rt)
#pragma unroll
      for (int ct = 0; ct < 2; ++ct)
        acc[rt][ct] = MFMA16(a[rt], b[ct], acc[rt][ct]);
  }

  {
    const float b1v0 = b1[n0], b1v1 = b1[n0 + 16];
#pragma unroll
    for (int rt = 0; rt < 4; ++rt)
#pragma unroll
      for (int ct = 0; ct < 2; ++ct) {
        const float bb = ct ? b1v1 : b1v0;
#pragma unroll
        for (int j = 0; j < 4; ++j) {
          float v = acc[rt][ct][j] + bb;
          v = v / (1.f + __expf(-v));
          hl[(rt * 16 + rowh + j) * HSTR + n0 + ct * 16] = f2bf(v);
        }
      }
  }
  __syncthreads();

  f32x4 acc2[4][2] = {};
#pragma unroll
  for (int ks = 0; ks < 4; ++ks) {
    const int k0 = ks * 32;
    bf16x8 a[4], b[2];
#pragma unroll
    for (int rt = 0; rt < 4; ++rt)
      a[rt] = *reinterpret_cast<const bf16x8*>(&hl[(rt * 16 + lr) * HSTR + k0 + lk]);
#pragma unroll
    for (int ct = 0; ct < 2; ++ct)
      b[ct] = *reinterpret_cast<const bf16x8*>(&W2T[(size_t)(n0 + ct * 16) * 128 + k0 + lk]);
#pragma unroll
    for (int rt = 0; rt < 4; ++rt)
#pragma unroll
      for (int ct = 0; ct < 2; ++ct)
        acc2[rt][ct] = MFMA16(a[rt], b[ct], acc2[rt][ct]);
  }

  {
    const float b2v0 = b2[n0], b2v1 = b2[n0 + 16];
#pragma unroll
    for (int rt = 0; rt < 4; ++rt)
#pragma unroll
      for (int j = 0; j < 4; ++j) {
        const int row = rt * 16 + rowh + j;
        const int dst = svw[row];
        if (dst >= 0) {
          unsafeAtomicAdd(&agg[(size_t)dst * 128 + n0], acc2[rt][0][j] + b2v0);
          unsafeAtomicAdd(&agg[(size_t)dst * 128 + n0 + 16], acc2[rt][1][j] + b2v1);
        }
      }
  }
}

__global__ __launch_bounds__(256, 2) void k_pair(
    const float* __restrict__ h_pair,
    const u16* __restrict__ W1T, const u16* __restrict__ W2T,
    const float* __restrict__ b1, const float* __restrict__ b2,
    float* __restrict__ out) {
  __shared__ __align__(16) u16 xl[64 * X2STR];
  __shared__ __align__(16) u16 hl[64 * HSTR];

  const int tid = threadIdx.x;
  const int r0 = blockIdx.x * 64;

  {
    const int row = tid >> 2, q = tid & 3;
    const int r = r0 + row;
    const int rc = (r < NP) ? r : (NP - 1);
    const float4* s1 = reinterpret_cast<const float4*>(h_pair + (size_t)rc * 128 + q * 32);
    const float4* s2 = reinterpret_cast<const float4*>(out + (size_t)rc * 128 + q * 32);
    u16* d1 = &xl[row * X2STR + q * 32];
    u16* d2 = &xl[row * X2STR + 128 + q * 32];
#pragma unroll
    for (int i = 0; i < 8; ++i) {
      *reinterpret_cast<ushort4*>(d1 + i * 4) = cvt4(s1[i]);
      *reinterpret_cast<ushort4*>(d2 + i * 4) = cvt4(s2[i]);
    }
  }
  __syncthreads();

  const int w = tid >> 6;
  const int l = tid & 63;
  const int lr = l & 15;
  const int lk = (l >> 4) << 3;
  const int n0 = w * 32 + lr;
  const int rowh = (l >> 4) << 2;

  f32x4 acc[4][2] = {};
#pragma unroll 1
  for (int ks = 0; ks < 8; ++ks) {
    const int k0 = ks * 32;
    bf16x8 a[4], b[2];
#pragma unroll
    for (int rt = 0; rt < 4; ++rt)
      a[rt] = *reinterpret_cast<const bf16x8*>(&xl[(rt * 16 + lr) * X2STR + k0 + lk]);
#pragma unroll
    for (int ct = 0; ct < 2; ++ct)
      b[ct] = *reinterpret_cast<const bf16x8*>(&W1T[(size_t)(n0 + ct * 16) * 256 + k0 + lk]);
#pragma unroll
    for (int rt = 0; rt < 4; ++rt)
#pragma unroll
      for (int ct = 0; ct < 2; ++ct)
        acc[rt][ct] = MFMA16(a[rt], b[ct], acc[rt][ct]);
  }

  {
    const float b1v0 = b1[n0], b1v1 = b1[n0 + 16];
#pragma unroll
    for (int rt = 0; rt < 4; ++rt)
#pragma unroll
      for (int ct = 0; ct < 2; ++ct) {
        const float bb = ct ? b1v1 : b1v0;
#pragma unroll
        for (int j = 0; j < 4; ++j) {
          float v = acc[rt][ct][j] + bb;
          v = v / (1.f + __expf(-v));
          hl[(rt * 16 + rowh + j) * HSTR + n0 + ct * 16] = f2bf(v);
        }
      }
  }
  __syncthreads();

  f32x4 acc2[4][2] = {};
#pragma unroll
  for (int ks = 0; ks < 4; ++ks) {
    const int k0 = ks * 32;
    bf16x8 a[4], b[2];
#pragma unroll
    for (int rt = 0; rt < 4; ++rt)
      a[rt] = *reinterpret_cast<const bf16x8*>(&hl[(rt * 16 + lr) * HSTR + k0 + lk]);
#pragma unroll
    for (int ct = 0; ct < 2; ++ct)
      b[ct] = *reinterpret_cast<const bf16x8*>(&W2T[(size_t)(n0 + ct * 16) * 128 + k0 + lk]);
#pragma unroll
    for (int rt = 0; rt < 4; ++rt)
#pragma unroll
      for (int ct = 0; ct < 2; ++ct)
        acc2[rt][ct] = MFMA16(a[rt], b[ct], acc2[rt][ct]);
  }

  {
    const float b2v0 = b2[n0], b2v1 = b2[n0 + 16];
#pragma unroll
    for (int rt = 0; rt < 4; ++rt)
#pragma unroll
      for (int j = 0; j < 4; ++j) {
        const int row = rt * 16 + rowh + j;
        const int r = r0 + row;
        if (r < NP) {
          out[(size_t)r * 128 + n0]      = h_pair[(size_t)r * 128 + n0]      + acc2[rt][0][j] + b2v0;
          out[(size_t)r * 128 + n0 + 16] = h_pair[(size_t)r * 128 + n0 + 16] + acc2[rt][1][j] + b2v1;
        }
      }
  }
}

extern "C" void kernel_launch(void* const* d_in, const int* in_sizes, int n_in,
                              void* d_out, int out_size, void* d_ws, size_t ws_size,
                              hipStream_t stream) {
  const float* h_pair = (const float*)d_in[0];
  const int* ivu = (const int*)d_in[1];
  const int* iuw = (const int*)d_in[2];
  const int* ivw = (const int*)d_in[3];
  const float* geom = (const float*)d_in[4];
  const float* psi_w1 = (const float*)d_in[5];
  const float* psi_b1 = (const float*)d_in[6];
  const float* psi_w2 = (const float*)d_in[7];
  const float* psi_b2 = (const float*)d_in[8];
  const float* phi_w1 = (const float*)d_in[9];
  const float* phi_b1 = (const float*)d_in[10];
  const float* phi_w2 = (const float*)d_in[11];
  const float* phi_b2 = (const float*)d_in[12];

  float* out = (float*)d_out;
  u16* ws = (u16*)d_ws;
  char* wsb = (char*)d_ws;

  if (ws_size >= WS_S3) {
    int*  cnt    = (int*)(wsb + SB_CNT2);
    int*  cursor = (int*)(wsb + SB_CURSOR2);
    int*  bsum   = (int*)(wsb + SB_BSUM2);
    int4* trip   = (int4*)(wsb + SB_TRIP);
    u32*  YA     = (u32*)(wsb + SB_YA);
    u32*  YB     = (u32*)(wsb + SB_YB);
    u32*  YC     = (u32*)(wsb + SB_YC);

    hipMemsetAsync(cnt, 0, NP * sizeof(int), stream);
    k_pre3<<<5529, 256, 0, stream>>>(psi_w1, psi_w2, phi_w1, phi_w2, ivw, ws, cnt);
    k_scan1<<<98, 1024, 0, stream>>>(cnt, cursor, bsum);
    k_scan2<<<1, 128, 0, stream>>>(bsum);
    k_perm_pack<<<1954, 256, 0, stream>>>(ivu, iuw, ivw, geom, cursor, bsum, trip);
    k_proj<<<1563, 256, 0, stream>>>(h_pair, ws + FP_W1A, ws + FP_W1B, ws + FP_W1C,
                                     ws + FP_H, YA, YB, YC);
    k_gsilu2<<<(NBATCH + 3) / 4, 256, 0, stream>>>(
        YA, YB, YC, (const u32*)trip,
        reinterpret_cast<const float*>(ws + FP_W1D), psi_b1, ws + FP_AGG);
    k_pair2<<<1563, 256, 0, stream>>>(
        h_pair, ws + FP_H, ws + FP_AGG, cnt, ws + FP_W2,
        ws + FP_PW1, ws + FP_PW2, psi_b2, phi_b1, phi_b2, out);
  } else {
    hipMemsetAsync(d_out, 0, (size_t)out_size * sizeof(float), stream);
    k_prep<<<(WS_U16_TOTAL + 255) / 256, 256, 0, stream>>>(psi_w1, psi_w2, phi_w1, phi_w2, ws);
    k_triplet<<<(T_TRIP + 63) / 64, 256, 0, stream>>>(
        h_pair, ivu, iuw, ivw, geom,
        ws + PSI_W1T_OFF, ws + PSI_W2T_OFF, psi_b1, psi_b2, out);
    k_pair<<<(NP + 63) / 64, 256, 0, stream>>>(
        h_pair, ws + PHI_W1T_OFF, ws + PHI_W2T_OFF, phi_b1, phi_b2, out);
  }
}